// Round 1
// baseline (883.583 us; speedup 1.0000x reference)
//
#include <hip/hip_runtime.h>
#include <math.h>

#define NN 100000
#define EE 1600000
#define GG 256
#define HH 128
#define NB_SCAN 98   /* ceil(NN/1024) */

// ---------------------------------------------------------------------------
// dtype layout detection: reference uses int64 for edge_index/batch. The
// harness contract says "integer -> const int*", but we defend against the
// buffers actually holding int64 (little-endian: low word at even int32 idx,
// high word (==0 for values < 2^31) at odd idx).
// flags[0] = edge_index is int64-layout; flags[1] = batch is int64-layout.
// ---------------------------------------------------------------------------
__global__ void detect_k(const int* __restrict__ ei, const int* __restrict__ batch,
                         int* __restrict__ flags) {
    if (threadIdx.x == 0 && blockIdx.x == 0) {
        // Sample 8 odd positions near the end of the 2E-int32 view.
        // int32 layout: these are random dst values in [0,100000) -> all-zero
        // probability ~1e-40. int64 layout: they are high words == 0.
        int e64 = 1;
        for (int j = 0; j < 8; ++j) {
            if (ei[2 * EE - 1 - 2 * j] != 0) { e64 = 0; break; }
        }
        flags[0] = e64;
        // batch sorted, last graph ~255. int32 layout: batch[NN-1] != 0 w.h.p.
        // int64 layout: index NN-1 (odd) is a high word == 0.
        flags[1] = (batch[NN - 1] == 0) ? 1 : 0;
    }
}

// ---------------------------------------------------------------------------
// degree histogram over dst (self-loops added later as +1)
// ---------------------------------------------------------------------------
__global__ __launch_bounds__(256) void deg_k(const int* __restrict__ ei,
                                             const int* __restrict__ flags,
                                             int* __restrict__ degcnt) {
    const int e = blockIdx.x * 256 + threadIdx.x;
    if (e < EE) {
        const bool e64 = flags[0] != 0;
        const int d = e64 ? ei[2 * (EE + e)] : ei[EE + e];
        atomicAdd(&degcnt[d], 1);
    }
}

__global__ __launch_bounds__(256) void dinv_k(const int* __restrict__ degcnt,
                                              float* __restrict__ dinv) {
    const int i = blockIdx.x * 256 + threadIdx.x;
    if (i < NN) {
        // deg includes the self-loop (+1), so always >= 1
        dinv[i] = 1.0f / sqrtf((float)(degcnt[i] + 1));
    }
}

// ---------------------------------------------------------------------------
// exclusive scan of degcnt -> offs (3-kernel two-level scan), cursor copy
// ---------------------------------------------------------------------------
__global__ __launch_bounds__(256) void scan1_k(const int* __restrict__ cnt,
                                               int* __restrict__ offs,
                                               int* __restrict__ partials) {
    __shared__ int sd[256];
    const int tid = threadIdx.x;
    const int i0 = blockIdx.x * 1024 + tid * 4;
    int c0 = (i0 + 0 < NN) ? cnt[i0 + 0] : 0;
    int c1 = (i0 + 1 < NN) ? cnt[i0 + 1] : 0;
    int c2 = (i0 + 2 < NN) ? cnt[i0 + 2] : 0;
    int c3 = (i0 + 3 < NN) ? cnt[i0 + 3] : 0;
    const int tsum = c0 + c1 + c2 + c3;
    sd[tid] = tsum;
    __syncthreads();
    for (int off = 1; off < 256; off <<= 1) {
        int t = (tid >= off) ? sd[tid - off] : 0;
        __syncthreads();
        sd[tid] += t;
        __syncthreads();
    }
    const int incl = sd[tid];
    const int ex = incl - tsum;
    if (i0 + 0 < NN) offs[i0 + 0] = ex;
    if (i0 + 1 < NN) offs[i0 + 1] = ex + c0;
    if (i0 + 2 < NN) offs[i0 + 2] = ex + c0 + c1;
    if (i0 + 3 < NN) offs[i0 + 3] = ex + c0 + c1 + c2;
    if (tid == 255) partials[blockIdx.x] = incl;
}

__global__ __launch_bounds__(128) void scan2_k(int* __restrict__ partials) {
    __shared__ int sd[128];
    const int tid = threadIdx.x;
    const int v = (tid < NB_SCAN) ? partials[tid] : 0;
    sd[tid] = v;
    __syncthreads();
    for (int off = 1; off < 128; off <<= 1) {
        int t = (tid >= off) ? sd[tid - off] : 0;
        __syncthreads();
        sd[tid] += t;
        __syncthreads();
    }
    if (tid < NB_SCAN) partials[tid] = sd[tid] - v;  // exclusive
}

__global__ __launch_bounds__(256) void scan3_k(int* __restrict__ offs,
                                               const int* __restrict__ partials,
                                               int* __restrict__ cursor) {
    const int i = blockIdx.x * 256 + threadIdx.x;
    if (i < NN) {
        const int o = offs[i] + partials[i >> 10];
        offs[i] = o;
        cursor[i] = o;
    }
}

// ---------------------------------------------------------------------------
// CSR bucket scatter: csr_src[pos] = src, bucketed by dst
// ---------------------------------------------------------------------------
__global__ __launch_bounds__(256) void scatter_k(const int* __restrict__ ei,
                                                 const int* __restrict__ flags,
                                                 int* __restrict__ cursor,
                                                 int* __restrict__ csr) {
    const int e = blockIdx.x * 256 + threadIdx.x;
    if (e < EE) {
        const bool e64 = flags[0] != 0;
        const int s = e64 ? ei[2 * e] : ei[e];
        const int d = e64 ? ei[2 * (EE + e)] : ei[EE + e];
        const int pos = atomicAdd(&cursor[d], 1);
        csr[pos] = s;
    }
}

// ---------------------------------------------------------------------------
// f32 GEMM: C[M,128] = A[M,128] @ B[128,128]. BM=64, BN=128, BK=16,
// 256 threads, 4x8 register tile per thread.
// ---------------------------------------------------------------------------
static __device__ __forceinline__ float sani(float v) {
    if (isnan(v)) return 0.0f;
    if (isinf(v)) return v > 0.0f ? 1e6f : -1e6f;
    return v;
}

template <bool SANITIZE>
__global__ __launch_bounds__(256) void gemm128_k(const float* __restrict__ A,
                                                 const float* __restrict__ B,
                                                 float* __restrict__ C, int M) {
    __shared__ float As[16][68];    // transposed: As[k][row], stride 68 (16B-aligned rows)
    __shared__ float Bs[16][132];   // Bs[k][col], stride 132 (16B-aligned rows)
    const int tid = threadIdx.x;
    const int tx = tid & 15;   // col group: cols tx*8 .. tx*8+7
    const int ty = tid >> 4;   // row group: rows ty*4 .. ty*4+3
    const int row0 = blockIdx.x * 64;

    float acc[4][8];
#pragma unroll
    for (int i = 0; i < 4; ++i)
#pragma unroll
        for (int j = 0; j < 8; ++j) acc[i][j] = 0.0f;

    const int lrow = tid >> 2;  // 0..63 (A staging row)
    const int lseg = tid & 3;   // 0..3  (A staging k-quad)
    const int arow = row0 + lrow;

    for (int kt = 0; kt < 8; ++kt) {
        float4 av = make_float4(0.f, 0.f, 0.f, 0.f);
        if (arow < M) {
            av = *(const float4*)(A + (size_t)arow * HH + kt * 16 + lseg * 4);
            if (SANITIZE) {
                av.x = sani(av.x); av.y = sani(av.y);
                av.z = sani(av.z); av.w = sani(av.w);
            }
        }
        const int f0 = tid,        k0 = f0 >> 5, c0 = (f0 & 31) * 4;
        const int f1 = tid + 256,  k1 = f1 >> 5, c1 = (f1 & 31) * 4;
        const float4 bv0 = *(const float4*)(B + (size_t)(kt * 16 + k0) * HH + c0);
        const float4 bv1 = *(const float4*)(B + (size_t)(kt * 16 + k1) * HH + c1);

        __syncthreads();
        As[lseg * 4 + 0][lrow] = av.x;
        As[lseg * 4 + 1][lrow] = av.y;
        As[lseg * 4 + 2][lrow] = av.z;
        As[lseg * 4 + 3][lrow] = av.w;
        *(float4*)&Bs[k0][c0] = bv0;
        *(float4*)&Bs[k1][c1] = bv1;
        __syncthreads();

#pragma unroll
        for (int k = 0; k < 16; ++k) {
            const float4 a  = *(const float4*)&As[k][ty * 4];
            const float4 b0 = *(const float4*)&Bs[k][tx * 8];
            const float4 b1 = *(const float4*)&Bs[k][tx * 8 + 4];
            const float aa[4] = {a.x, a.y, a.z, a.w};
            const float bb[8] = {b0.x, b0.y, b0.z, b0.w, b1.x, b1.y, b1.z, b1.w};
#pragma unroll
            for (int i = 0; i < 4; ++i)
#pragma unroll
                for (int j = 0; j < 8; ++j) acc[i][j] += aa[i] * bb[j];
        }
    }

#pragma unroll
    for (int i = 0; i < 4; ++i) {
        const int r = row0 + ty * 4 + i;
        if (r < M) {
            *(float4*)(C + (size_t)r * HH + tx * 8) =
                make_float4(acc[i][0], acc[i][1], acc[i][2], acc[i][3]);
            *(float4*)(C + (size_t)r * HH + tx * 8 + 4) =
                make_float4(acc[i][4], acc[i][5], acc[i][6], acc[i][7]);
        }
    }
}

// ---------------------------------------------------------------------------
// Fused aggregate + bias + BN(eval) + ReLU. One wave per node, lane owns
// channels (2*lane, 2*lane+1) as float2. out = relu((agg + b - m)*scale + be)
// where agg = dinv[v]*(sum_e dinv[s]*h[s]) + dinv[v]^2*h[v].
// ---------------------------------------------------------------------------
__global__ __launch_bounds__(256) void aggregate_k(
    const float* __restrict__ hpre, const int* __restrict__ csr,
    const int* __restrict__ offs, const int* __restrict__ cnt,
    const float* __restrict__ dinv,
    const float* __restrict__ bias, const float* __restrict__ gamma,
    const float* __restrict__ beta, const float* __restrict__ mean,
    const float* __restrict__ var, float* __restrict__ xout) {
    const int v = __builtin_amdgcn_readfirstlane(blockIdx.x * 4 + (threadIdx.x >> 6));
    const int lane = threadIdx.x & 63;
    const int c0 = lane * 2, c1 = lane * 2 + 1;

    const float dv = dinv[v];
    const int start = offs[v];
    const int n = cnt[v];
    const float2* __restrict__ h2 = (const float2*)hpre;

    float ax = 0.0f, ay = 0.0f;
    int i = 0;
    for (; i + 4 <= n; i += 4) {
        const int s0 = csr[start + i + 0];
        const int s1 = csr[start + i + 1];
        const int s2 = csr[start + i + 2];
        const int s3 = csr[start + i + 3];
        const float w0 = dinv[s0], w1 = dinv[s1], w2 = dinv[s2], w3 = dinv[s3];
        const float2 a0 = h2[(size_t)s0 * 64 + lane];
        const float2 a1 = h2[(size_t)s1 * 64 + lane];
        const float2 a2 = h2[(size_t)s2 * 64 + lane];
        const float2 a3 = h2[(size_t)s3 * 64 + lane];
        ax += w0 * a0.x + w1 * a1.x + w2 * a2.x + w3 * a3.x;
        ay += w0 * a0.y + w1 * a1.y + w2 * a2.y + w3 * a3.y;
    }
    for (; i < n; ++i) {
        const int s = csr[start + i];
        const float w = dinv[s];
        const float2 a = h2[(size_t)s * 64 + lane];
        ax += w * a.x;
        ay += w * a.y;
    }
    const float2 hs = h2[(size_t)v * 64 + lane];
    ax = dv * ax + dv * dv * hs.x;
    ay = dv * ay + dv * dv * hs.y;

    const float sc0 = gamma[c0] / sqrtf(var[c0] + 1e-5f);
    const float sc1 = gamma[c1] / sqrtf(var[c1] + 1e-5f);
    const float y0 = fmaxf((ax + bias[c0] - mean[c0]) * sc0 + beta[c0], 0.0f);
    const float y1 = fmaxf((ay + bias[c1] - mean[c1]) * sc1 + beta[c1], 0.0f);
    ((float2*)xout)[(size_t)v * 64 + lane] = make_float2(y0, y1);
}

// ---------------------------------------------------------------------------
// Global mean pool (batch is sorted) + 2-layer FC head, one block per graph.
// ---------------------------------------------------------------------------
__global__ __launch_bounds__(128) void pool_head_k(
    const float* __restrict__ x, const int* __restrict__ batch,
    const int* __restrict__ flags,
    const float* __restrict__ fw1, const float* __restrict__ fb1,
    const float* __restrict__ fw2, const float* __restrict__ fb2,
    float* __restrict__ out) {
    __shared__ float pooled[128];
    __shared__ float hid[64];
    const int g = blockIdx.x;
    const int tid = threadIdx.x;
    const bool b64 = flags[1] != 0;

    // lower_bound over sorted batch
    int lo = 0, hi = NN;
    while (lo < hi) {
        const int mid = (lo + hi) >> 1;
        const int bv = b64 ? batch[2 * mid] : batch[mid];
        if (bv < g) lo = mid + 1; else hi = mid;
    }
    const int beg = lo;
    lo = beg; hi = NN;
    while (lo < hi) {
        const int mid = (lo + hi) >> 1;
        const int bv = b64 ? batch[2 * mid] : batch[mid];
        if (bv < g + 1) lo = mid + 1; else hi = mid;
    }
    const int end = lo;
    const int cntn = end - beg;

    float s0 = 0.f, s1 = 0.f, s2 = 0.f, s3 = 0.f;
    int i = beg;
    for (; i + 4 <= end; i += 4) {
        s0 += x[(size_t)(i + 0) * HH + tid];
        s1 += x[(size_t)(i + 1) * HH + tid];
        s2 += x[(size_t)(i + 2) * HH + tid];
        s3 += x[(size_t)(i + 3) * HH + tid];
    }
    for (; i < end; ++i) s0 += x[(size_t)i * HH + tid];
    const float s = (s0 + s1) + (s2 + s3);
    pooled[tid] = s / (float)(cntn > 0 ? cntn : 1);
    __syncthreads();

    if (tid < 64) {
        float a = fb1[tid];
#pragma unroll 4
        for (int k = 0; k < 128; ++k) a += pooled[k] * fw1[k * 64 + tid];
        hid[tid] = fmaxf(a, 0.0f);
    }
    __syncthreads();
    if (tid < 10) {
        float a = fb2[tid];
#pragma unroll
        for (int k = 0; k < 64; ++k) a += hid[k] * fw2[k * 10 + tid];
        out[g * 10 + tid] = a;
    }
}

// ---------------------------------------------------------------------------
// launch
// ---------------------------------------------------------------------------
extern "C" void kernel_launch(void* const* d_in, const int* in_sizes, int n_in,
                              void* d_out, int out_size, void* d_ws, size_t ws_size,
                              hipStream_t stream) {
    const float* x_in  = (const float*)d_in[0];
    const int*   ei    = (const int*)d_in[1];
    const int*   batch = (const int*)d_in[2];
    const float* w1 = (const float*)d_in[3];
    const float* b1 = (const float*)d_in[4];
    const float* w2 = (const float*)d_in[5];
    const float* b2 = (const float*)d_in[6];
    const float* w3 = (const float*)d_in[7];
    const float* b3 = (const float*)d_in[8];
    const float* g1 = (const float*)d_in[9];
    const float* be1 = (const float*)d_in[10];
    const float* m1 = (const float*)d_in[11];
    const float* v1 = (const float*)d_in[12];
    const float* g2 = (const float*)d_in[13];
    const float* be2 = (const float*)d_in[14];
    const float* m2 = (const float*)d_in[15];
    const float* v2 = (const float*)d_in[16];
    const float* g3 = (const float*)d_in[17];
    const float* be3 = (const float*)d_in[18];
    const float* m3 = (const float*)d_in[19];
    const float* v3 = (const float*)d_in[20];
    const float* fw1 = (const float*)d_in[21];
    const float* fb1 = (const float*)d_in[22];
    const float* fw2 = (const float*)d_in[23];
    const float* fb2 = (const float*)d_in[24];
    float* out = (float*)d_out;

    // workspace carve-up (256B aligned)
    size_t off = 0;
    char* base = (char*)d_ws;
    auto alloc = [&](size_t bytes) -> void* {
        void* p = base + off;
        off += (bytes + 255) & ~(size_t)255;
        return p;
    };
    int*   degcnt   = (int*)alloc((size_t)NN * 4);
    float* dinv     = (float*)alloc((size_t)NN * 4);
    int*   offs     = (int*)alloc((size_t)NN * 4);
    int*   cursor   = (int*)alloc((size_t)NN * 4);
    int*   partials = (int*)alloc(128 * 4);
    int*   flags    = (int*)alloc(256);
    int*   csr      = (int*)alloc((size_t)EE * 4);
    float* bufx     = (float*)alloc((size_t)NN * HH * 4);
    float* hpre     = (float*)alloc((size_t)NN * HH * 4);
    if (off > ws_size) return;  // workspace too small -> loud failure

    hipMemsetAsync(degcnt, 0, (size_t)NN * 4, stream);
    detect_k<<<1, 64, 0, stream>>>(ei, batch, flags);

    const int egrid = (EE + 255) / 256;
    const int ngrid = (NN + 255) / 256;
    deg_k<<<egrid, 256, 0, stream>>>(ei, flags, degcnt);
    dinv_k<<<ngrid, 256, 0, stream>>>(degcnt, dinv);
    scan1_k<<<NB_SCAN, 256, 0, stream>>>(degcnt, offs, partials);
    scan2_k<<<1, 128, 0, stream>>>(partials);
    scan3_k<<<ngrid, 256, 0, stream>>>(offs, partials, cursor);
    scatter_k<<<egrid, 256, 0, stream>>>(ei, flags, cursor, csr);

    const int ggrid = (NN + 63) / 64;          // 1563
    const int agrid = NN / 4;                  // 25000 (NN divisible by 4)

    // layer 1 (sanitize input x)
    gemm128_k<true><<<ggrid, 256, 0, stream>>>(x_in, w1, hpre, NN);
    aggregate_k<<<agrid, 256, 0, stream>>>(hpre, csr, offs, degcnt, dinv,
                                           b1, g1, be1, m1, v1, bufx);
    // layer 2
    gemm128_k<false><<<ggrid, 256, 0, stream>>>(bufx, w2, hpre, NN);
    aggregate_k<<<agrid, 256, 0, stream>>>(hpre, csr, offs, degcnt, dinv,
                                           b2, g2, be2, m2, v2, bufx);
    // layer 3
    gemm128_k<false><<<ggrid, 256, 0, stream>>>(bufx, w3, hpre, NN);
    aggregate_k<<<agrid, 256, 0, stream>>>(hpre, csr, offs, degcnt, dinv,
                                           b3, g3, be3, m3, v3, bufx);

    pool_head_k<<<GG, 128, 0, stream>>>(bufx, batch, flags,
                                        fw1, fb1, fw2, fb2, out);
}

// Round 2
// 749.719 us; speedup vs baseline: 1.1786x; 1.1786x over previous
//
#include <hip/hip_runtime.h>
#include <math.h>

#define NN 100000
#define EE 1600000
#define GG 256
#define HH 128
#define BSH 8                 /* 256 nodes per bucket */
#define NBK 391               /* ceil(NN/256) */
#define PASSA_WG 391          /* ceil(EE/4096) */
#define CAP 6144              /* staged pairs per bucket (avg 4092, +30 sigma) */

// ---------------------------------------------------------------------------
// dtype layout detection: reference uses int64 for edge_index/batch; defend
// against either int32 or int64 device layout (little-endian high words == 0).
// ---------------------------------------------------------------------------
__global__ void detect_k(const int* __restrict__ ei, const int* __restrict__ batch,
                         int* __restrict__ flags) {
    if (threadIdx.x == 0 && blockIdx.x == 0) {
        int e64 = 1;
        for (int j = 0; j < 8; ++j) {
            if (ei[2 * EE - 1 - 2 * j] != 0) { e64 = 0; break; }
        }
        flags[0] = e64;
        flags[1] = (batch[NN - 1] == 0) ? 1 : 0;
    }
}

// ---------------------------------------------------------------------------
// P1: bucket histogram over dst (LDS-aggregated; 391 global atomics per wg)
// ---------------------------------------------------------------------------
__global__ __launch_bounds__(256) void bhist_k(const int* __restrict__ ei,
                                               const int* __restrict__ flags,
                                               int* __restrict__ bcnt) {
    __shared__ int h[NBK];
    for (int i = threadIdx.x; i < NBK; i += 256) h[i] = 0;
    __syncthreads();
    const bool e64 = flags[0] != 0;
    const int base = blockIdx.x * 4096;
#pragma unroll
    for (int j = 0; j < 16; ++j) {
        const int e = base + j * 256 + threadIdx.x;
        if (e < EE) {
            const int d = e64 ? ei[2 * (EE + e)] : ei[EE + e];
            atomicAdd(&h[d >> BSH], 1);
        }
    }
    __syncthreads();
    for (int i = threadIdx.x; i < NBK; i += 256)
        if (h[i]) atomicAdd(&bcnt[i], h[i]);
}

// ---------------------------------------------------------------------------
// P2: scan 391 bucket counts -> bbase[392] (exclusive), cursor = base copy
// ---------------------------------------------------------------------------
__global__ __launch_bounds__(512) void bscan_k(const int* __restrict__ bcnt,
                                               int* __restrict__ bbase,
                                               int* __restrict__ cursor) {
    __shared__ int sd[512];
    const int tid = threadIdx.x;
    const int v = (tid < NBK) ? bcnt[tid] : 0;
    sd[tid] = v;
    __syncthreads();
    for (int off = 1; off < 512; off <<= 1) {
        int t = (tid >= off) ? sd[tid - off] : 0;
        __syncthreads();
        sd[tid] += t;
        __syncthreads();
    }
    if (tid < NBK) {
        bbase[tid + 1] = sd[tid];          // inclusive -> bbase[i+1]
        cursor[tid] = sd[tid] - v;         // exclusive base
    }
    if (tid == 0) bbase[0] = 0;
}

// ---------------------------------------------------------------------------
// P3 (pass A): bucket-grouped pair scatter. Each wg: LDS count -> one range
// reservation atomic per (wg,bucket) -> contiguous pair writes per bucket.
// ---------------------------------------------------------------------------
__global__ __launch_bounds__(256) void passA_k(const int* __restrict__ ei,
                                               const int* __restrict__ flags,
                                               int* __restrict__ cursor,
                                               uint2* __restrict__ pairs) {
    __shared__ int h[NBK];
    __shared__ int rbase[NBK];
    const int tid = threadIdx.x;
    for (int i = tid; i < NBK; i += 256) h[i] = 0;
    __syncthreads();
    const bool e64 = flags[0] != 0;
    const int base = blockIdx.x * 4096;
    int scache[16], dcache[16];
#pragma unroll
    for (int j = 0; j < 16; ++j) {
        const int e = base + j * 256 + tid;
        int s = -1, d = 0;
        if (e < EE) {
            s = e64 ? ei[2 * e] : ei[e];
            d = e64 ? ei[2 * (EE + e)] : ei[EE + e];
            atomicAdd(&h[d >> BSH], 1);
        }
        scache[j] = s; dcache[j] = d;
    }
    __syncthreads();
    for (int i = tid; i < NBK; i += 256) {
        const int c = h[i];
        rbase[i] = c ? atomicAdd(&cursor[i], c) : 0;
    }
    __syncthreads();
    for (int i = tid; i < NBK; i += 256) h[i] = 0;
    __syncthreads();
#pragma unroll
    for (int j = 0; j < 16; ++j) {
        const int s = scache[j];
        if (s >= 0) {
            const int d = dcache[j];
            const int b = d >> BSH;
            const int r = atomicAdd(&h[b], 1);
            pairs[rbase[b] + r] = make_uint2((unsigned)s, (unsigned)d);
        }
    }
}

// ---------------------------------------------------------------------------
// P4 (pass B): one wg per bucket. Stage pairs in LDS, per-node count + scan
// -> offs/degcnt/dinv, then LDS-ranked scatter into the bucket's CSR region.
// ---------------------------------------------------------------------------
__global__ __launch_bounds__(256) void passB_k(const uint2* __restrict__ pairs,
                                               const int* __restrict__ bbase,
                                               int* __restrict__ offs,
                                               int* __restrict__ degcnt,
                                               float* __restrict__ dinv,
                                               int* __restrict__ csr) {
    __shared__ unsigned src_s[CAP];
    __shared__ unsigned char dloc_s[CAP];
    __shared__ int cnt[256];
    __shared__ int loff[256];
    __shared__ int sc[256];
    const int tid = threadIdx.x;
    const int b = blockIdx.x;
    const int p0 = bbase[b];
    const int np = bbase[b + 1] - p0;
    const int nb0 = b << BSH;
    const int nnode = (NN - nb0 < 256) ? (NN - nb0) : 256;

    cnt[tid] = 0;
    __syncthreads();
    for (int i = tid; i < np; i += 256) {
        const uint2 p = pairs[p0 + i];
        const int dl = (int)p.y - nb0;
        atomicAdd(&cnt[dl], 1);
        if (i < CAP) { src_s[i] = p.x; dloc_s[i] = (unsigned char)dl; }
    }
    __syncthreads();
    // exclusive scan of cnt -> loff
    sc[tid] = cnt[tid];
    __syncthreads();
    for (int off = 1; off < 256; off <<= 1) {
        int t = (tid >= off) ? sc[tid - off] : 0;
        __syncthreads();
        sc[tid] += t;
        __syncthreads();
    }
    const int ex = sc[tid] - cnt[tid];
    loff[tid] = ex;
    if (tid < nnode) {
        const int node = nb0 + tid;
        offs[node] = p0 + ex;
        degcnt[node] = cnt[tid];
        dinv[node] = 1.0f / sqrtf((float)(cnt[tid] + 1));
    }
    __syncthreads();
    cnt[tid] = 0;
    __syncthreads();
    for (int i = tid; i < np; i += 256) {
        unsigned s; int dl;
        if (i < CAP) { s = src_s[i]; dl = (int)dloc_s[i]; }
        else { const uint2 p = pairs[p0 + i]; s = p.x; dl = (int)p.y - nb0; }
        const int r = atomicAdd(&cnt[dl], 1);
        csr[p0 + loff[dl] + r] = (int)s;
    }
}

// ---------------------------------------------------------------------------
// f32 GEMM: C[M,128] = A[M,128] @ B[128,128]. BM=64, BN=128, BK=16,
// 256 threads, 4x8 register tile per thread.
// ---------------------------------------------------------------------------
static __device__ __forceinline__ float sani(float v) {
    if (isnan(v)) return 0.0f;
    if (isinf(v)) return v > 0.0f ? 1e6f : -1e6f;
    return v;
}

template <bool SANITIZE>
__global__ __launch_bounds__(256) void gemm128_k(const float* __restrict__ A,
                                                 const float* __restrict__ B,
                                                 float* __restrict__ C, int M) {
    __shared__ float As[16][68];
    __shared__ float Bs[16][132];
    const int tid = threadIdx.x;
    const int tx = tid & 15;
    const int ty = tid >> 4;
    const int row0 = blockIdx.x * 64;

    float acc[4][8];
#pragma unroll
    for (int i = 0; i < 4; ++i)
#pragma unroll
        for (int j = 0; j < 8; ++j) acc[i][j] = 0.0f;

    const int lrow = tid >> 2;
    const int lseg = tid & 3;
    const int arow = row0 + lrow;

    for (int kt = 0; kt < 8; ++kt) {
        float4 av = make_float4(0.f, 0.f, 0.f, 0.f);
        if (arow < M) {
            av = *(const float4*)(A + (size_t)arow * HH + kt * 16 + lseg * 4);
            if (SANITIZE) {
                av.x = sani(av.x); av.y = sani(av.y);
                av.z = sani(av.z); av.w = sani(av.w);
            }
        }
        const int f0 = tid,        k0 = f0 >> 5, c0 = (f0 & 31) * 4;
        const int f1 = tid + 256,  k1 = f1 >> 5, c1 = (f1 & 31) * 4;
        const float4 bv0 = *(const float4*)(B + (size_t)(kt * 16 + k0) * HH + c0);
        const float4 bv1 = *(const float4*)(B + (size_t)(kt * 16 + k1) * HH + c1);

        __syncthreads();
        As[lseg * 4 + 0][lrow] = av.x;
        As[lseg * 4 + 1][lrow] = av.y;
        As[lseg * 4 + 2][lrow] = av.z;
        As[lseg * 4 + 3][lrow] = av.w;
        *(float4*)&Bs[k0][c0] = bv0;
        *(float4*)&Bs[k1][c1] = bv1;
        __syncthreads();

#pragma unroll
        for (int k = 0; k < 16; ++k) {
            const float4 a  = *(const float4*)&As[k][ty * 4];
            const float4 b0 = *(const float4*)&Bs[k][tx * 8];
            const float4 b1 = *(const float4*)&Bs[k][tx * 8 + 4];
            const float aa[4] = {a.x, a.y, a.z, a.w};
            const float bb[8] = {b0.x, b0.y, b0.z, b0.w, b1.x, b1.y, b1.z, b1.w};
#pragma unroll
            for (int i = 0; i < 4; ++i)
#pragma unroll
                for (int j = 0; j < 8; ++j) acc[i][j] += aa[i] * bb[j];
        }
    }

#pragma unroll
    for (int i = 0; i < 4; ++i) {
        const int r = row0 + ty * 4 + i;
        if (r < M) {
            *(float4*)(C + (size_t)r * HH + tx * 8) =
                make_float4(acc[i][0], acc[i][1], acc[i][2], acc[i][3]);
            *(float4*)(C + (size_t)r * HH + tx * 8 + 4) =
                make_float4(acc[i][4], acc[i][5], acc[i][6], acc[i][7]);
        }
    }
}

// ---------------------------------------------------------------------------
// Fused aggregate + bias + BN(eval) + ReLU. One wave per node, lane owns
// channels (2*lane, 2*lane+1) as float2.
// ---------------------------------------------------------------------------
__global__ __launch_bounds__(256) void aggregate_k(
    const float* __restrict__ hpre, const int* __restrict__ csr,
    const int* __restrict__ offs, const int* __restrict__ cnt,
    const float* __restrict__ dinv,
    const float* __restrict__ bias, const float* __restrict__ gamma,
    const float* __restrict__ beta, const float* __restrict__ mean,
    const float* __restrict__ var, float* __restrict__ xout) {
    const int v = __builtin_amdgcn_readfirstlane(blockIdx.x * 4 + (threadIdx.x >> 6));
    const int lane = threadIdx.x & 63;
    const int c0 = lane * 2, c1 = lane * 2 + 1;

    const float dv = dinv[v];
    const int start = offs[v];
    const int n = cnt[v];
    const float2* __restrict__ h2 = (const float2*)hpre;

    float ax = 0.0f, ay = 0.0f;
    int i = 0;
    for (; i + 4 <= n; i += 4) {
        const int s0 = csr[start + i + 0];
        const int s1 = csr[start + i + 1];
        const int s2 = csr[start + i + 2];
        const int s3 = csr[start + i + 3];
        const float w0 = dinv[s0], w1 = dinv[s1], w2 = dinv[s2], w3 = dinv[s3];
        const float2 a0 = h2[(size_t)s0 * 64 + lane];
        const float2 a1 = h2[(size_t)s1 * 64 + lane];
        const float2 a2 = h2[(size_t)s2 * 64 + lane];
        const float2 a3 = h2[(size_t)s3 * 64 + lane];
        ax += w0 * a0.x + w1 * a1.x + w2 * a2.x + w3 * a3.x;
        ay += w0 * a0.y + w1 * a1.y + w2 * a2.y + w3 * a3.y;
    }
    for (; i < n; ++i) {
        const int s = csr[start + i];
        const float w = dinv[s];
        const float2 a = h2[(size_t)s * 64 + lane];
        ax += w * a.x;
        ay += w * a.y;
    }
    const float2 hs = h2[(size_t)v * 64 + lane];
    ax = dv * ax + dv * dv * hs.x;
    ay = dv * ay + dv * dv * hs.y;

    const float sc0 = gamma[c0] / sqrtf(var[c0] + 1e-5f);
    const float sc1 = gamma[c1] / sqrtf(var[c1] + 1e-5f);
    const float y0 = fmaxf((ax + bias[c0] - mean[c0]) * sc0 + beta[c0], 0.0f);
    const float y1 = fmaxf((ay + bias[c1] - mean[c1]) * sc1 + beta[c1], 0.0f);
    ((float2*)xout)[(size_t)v * 64 + lane] = make_float2(y0, y1);
}

// ---------------------------------------------------------------------------
// Global mean pool (batch is sorted) + 2-layer FC head, one block per graph.
// ---------------------------------------------------------------------------
__global__ __launch_bounds__(128) void pool_head_k(
    const float* __restrict__ x, const int* __restrict__ batch,
    const int* __restrict__ flags,
    const float* __restrict__ fw1, const float* __restrict__ fb1,
    const float* __restrict__ fw2, const float* __restrict__ fb2,
    float* __restrict__ out) {
    __shared__ float pooled[128];
    __shared__ float hid[64];
    const int g = blockIdx.x;
    const int tid = threadIdx.x;
    const bool b64 = flags[1] != 0;

    int lo = 0, hi = NN;
    while (lo < hi) {
        const int mid = (lo + hi) >> 1;
        const int bv = b64 ? batch[2 * mid] : batch[mid];
        if (bv < g) lo = mid + 1; else hi = mid;
    }
    const int beg = lo;
    lo = beg; hi = NN;
    while (lo < hi) {
        const int mid = (lo + hi) >> 1;
        const int bv = b64 ? batch[2 * mid] : batch[mid];
        if (bv < g + 1) lo = mid + 1; else hi = mid;
    }
    const int end = lo;
    const int cntn = end - beg;

    float s0 = 0.f, s1 = 0.f, s2 = 0.f, s3 = 0.f;
    int i = beg;
    for (; i + 4 <= end; i += 4) {
        s0 += x[(size_t)(i + 0) * HH + tid];
        s1 += x[(size_t)(i + 1) * HH + tid];
        s2 += x[(size_t)(i + 2) * HH + tid];
        s3 += x[(size_t)(i + 3) * HH + tid];
    }
    for (; i < end; ++i) s0 += x[(size_t)i * HH + tid];
    const float s = (s0 + s1) + (s2 + s3);
    pooled[tid] = s / (float)(cntn > 0 ? cntn : 1);
    __syncthreads();

    if (tid < 64) {
        float a = fb1[tid];
#pragma unroll 4
        for (int k = 0; k < 128; ++k) a += pooled[k] * fw1[k * 64 + tid];
        hid[tid] = fmaxf(a, 0.0f);
    }
    __syncthreads();
    if (tid < 10) {
        float a = fb2[tid];
#pragma unroll
        for (int k = 0; k < 64; ++k) a += hid[k] * fw2[k * 10 + tid];
        out[g * 10 + tid] = a;
    }
}

// ---------------------------------------------------------------------------
// launch
// ---------------------------------------------------------------------------
extern "C" void kernel_launch(void* const* d_in, const int* in_sizes, int n_in,
                              void* d_out, int out_size, void* d_ws, size_t ws_size,
                              hipStream_t stream) {
    const float* x_in  = (const float*)d_in[0];
    const int*   ei    = (const int*)d_in[1];
    const int*   batch = (const int*)d_in[2];
    const float* w1 = (const float*)d_in[3];
    const float* b1 = (const float*)d_in[4];
    const float* w2 = (const float*)d_in[5];
    const float* b2 = (const float*)d_in[6];
    const float* w3 = (const float*)d_in[7];
    const float* b3 = (const float*)d_in[8];
    const float* g1 = (const float*)d_in[9];
    const float* be1 = (const float*)d_in[10];
    const float* m1 = (const float*)d_in[11];
    const float* v1 = (const float*)d_in[12];
    const float* g2 = (const float*)d_in[13];
    const float* be2 = (const float*)d_in[14];
    const float* m2 = (const float*)d_in[15];
    const float* v2 = (const float*)d_in[16];
    const float* g3 = (const float*)d_in[17];
    const float* be3 = (const float*)d_in[18];
    const float* m3 = (const float*)d_in[19];
    const float* v3 = (const float*)d_in[20];
    const float* fw1 = (const float*)d_in[21];
    const float* fb1 = (const float*)d_in[22];
    const float* fw2 = (const float*)d_in[23];
    const float* fb2 = (const float*)d_in[24];
    float* out = (float*)d_out;

    // workspace carve-up (256B aligned)
    size_t off = 0;
    char* base = (char*)d_ws;
    auto alloc = [&](size_t bytes) -> void* {
        void* p = base + off;
        off += (bytes + 255) & ~(size_t)255;
        return p;
    };
    int*   degcnt = (int*)alloc((size_t)NN * 4);
    float* dinv   = (float*)alloc((size_t)NN * 4);
    int*   offs   = (int*)alloc((size_t)NN * 4);
    int*   bcnt   = (int*)alloc((size_t)NBK * 4);
    int*   bbase  = (int*)alloc((size_t)(NBK + 1) * 4);
    int*   cursor = (int*)alloc((size_t)NBK * 4);
    int*   flags  = (int*)alloc(256);
    int*   csr    = (int*)alloc((size_t)EE * 4);
    float* bufx   = (float*)alloc((size_t)NN * HH * 4);
    float* hpre   = (float*)alloc((size_t)NN * HH * 4);
    uint2* pairs  = (uint2*)hpre;   // alias: pairs dead before first gemm writes hpre
    if (off > ws_size) return;

    hipMemsetAsync(bcnt, 0, (size_t)NBK * 4, stream);
    detect_k<<<1, 64, 0, stream>>>(ei, batch, flags);

    bhist_k<<<PASSA_WG, 256, 0, stream>>>(ei, flags, bcnt);
    bscan_k<<<1, 512, 0, stream>>>(bcnt, bbase, cursor);
    passA_k<<<PASSA_WG, 256, 0, stream>>>(ei, flags, cursor, pairs);
    passB_k<<<NBK, 256, 0, stream>>>(pairs, bbase, offs, degcnt, dinv, csr);

    const int ggrid = (NN + 63) / 64;          // 1563
    const int agrid = NN / 4;                  // 25000

    gemm128_k<true><<<ggrid, 256, 0, stream>>>(x_in, w1, hpre, NN);
    aggregate_k<<<agrid, 256, 0, stream>>>(hpre, csr, offs, degcnt, dinv,
                                           b1, g1, be1, m1, v1, bufx);
    gemm128_k<false><<<ggrid, 256, 0, stream>>>(bufx, w2, hpre, NN);
    aggregate_k<<<agrid, 256, 0, stream>>>(hpre, csr, offs, degcnt, dinv,
                                           b2, g2, be2, m2, v2, bufx);
    gemm128_k<false><<<ggrid, 256, 0, stream>>>(bufx, w3, hpre, NN);
    aggregate_k<<<agrid, 256, 0, stream>>>(hpre, csr, offs, degcnt, dinv,
                                           b3, g3, be3, m3, v3, bufx);

    pool_head_k<<<GG, 128, 0, stream>>>(bufx, batch, flags,
                                        fw1, fb1, fw2, fb2, out);
}

// Round 3
// 675.431 us; speedup vs baseline: 1.3082x; 1.1100x over previous
//
#include <hip/hip_runtime.h>
#include <math.h>

#define NN 100000
#define EE 1600000
#define GG 256
#define HH 128
#define BSH 8                 /* 256 nodes per bucket */
#define NBK 391               /* ceil(NN/256) */
#define PASSA_WG 391          /* ceil(EE/4096) */
#define CAPB 5120             /* fixed region capacity per bucket (mean 4092, +16 sigma) */

// ---------------------------------------------------------------------------
// bf16 helpers (RNE pack, cheap unpack)
// ---------------------------------------------------------------------------
static __device__ __forceinline__ unsigned bf16rne(float f) {
    const unsigned u = __float_as_uint(f);
    return (u + 0x7fffu + ((u >> 16) & 1u)) >> 16;
}
static __device__ __forceinline__ unsigned packbf(float a, float b) {
    return bf16rne(a) | (bf16rne(b) << 16);
}
static __device__ __forceinline__ float bflo(unsigned u) { return __uint_as_float(u << 16); }
static __device__ __forceinline__ float bfhi(unsigned u) { return __uint_as_float(u & 0xffff0000u); }

// ---------------------------------------------------------------------------
// dtype layout detection (int32 vs int64 device layout for edge_index/batch)
// ---------------------------------------------------------------------------
__global__ void detect_k(const int* __restrict__ ei, const int* __restrict__ batch,
                         int* __restrict__ flags) {
    if (threadIdx.x == 0 && blockIdx.x == 0) {
        int e64 = 1;
        for (int j = 0; j < 8; ++j) {
            if (ei[2 * EE - 1 - 2 * j] != 0) { e64 = 0; break; }
        }
        flags[0] = e64;
        flags[1] = (batch[NN - 1] == 0) ? 1 : 0;
    }
}

// cursor[b] = b*CAPB (fixed per-bucket region bases)
__global__ __launch_bounds__(512) void cursinit_k(int* __restrict__ cursor) {
    const int b = blockIdx.x * 512 + threadIdx.x;
    if (b < NBK) cursor[b] = b * CAPB;
}

// ---------------------------------------------------------------------------
// pass A: bucket-grouped packed-pair scatter into fixed regions.
// packed = (dloc<<17) | src   (src < 2^17, dloc < 256)
// ---------------------------------------------------------------------------
__global__ __launch_bounds__(256) void passA_k(const int* __restrict__ ei,
                                               const int* __restrict__ flags,
                                               int* __restrict__ cursor,
                                               unsigned* __restrict__ pairs) {
    __shared__ int h[NBK];
    __shared__ int rbase[NBK];
    const int tid = threadIdx.x;
    for (int i = tid; i < NBK; i += 256) h[i] = 0;
    __syncthreads();
    const bool e64 = flags[0] != 0;
    const int base = blockIdx.x * 4096;
    int scache[16], dcache[16];
#pragma unroll
    for (int j = 0; j < 16; ++j) {
        const int e = base + j * 256 + tid;
        int s = -1, d = 0;
        if (e < EE) {
            s = e64 ? ei[2 * e] : ei[e];
            d = e64 ? ei[2 * (EE + e)] : ei[EE + e];
            atomicAdd(&h[d >> BSH], 1);
        }
        scache[j] = s; dcache[j] = d;
    }
    __syncthreads();
    for (int i = tid; i < NBK; i += 256) {
        const int c = h[i];
        rbase[i] = c ? atomicAdd(&cursor[i], c) : 0;
    }
    __syncthreads();
    for (int i = tid; i < NBK; i += 256) h[i] = 0;
    __syncthreads();
#pragma unroll
    for (int j = 0; j < 16; ++j) {
        const int s = scache[j];
        if (s >= 0) {
            const int d = dcache[j];
            const int b = d >> BSH;
            const int r = atomicAdd(&h[b], 1);
            pairs[rbase[b] + r] = ((unsigned)(d & 255) << 17) | (unsigned)s;
        }
    }
}

// ---------------------------------------------------------------------------
// pass B: one wg per bucket. Stage packed pairs in LDS, per-node count+scan
// -> offs/degcnt/dinv, LDS-ranked scatter into the bucket's CSR region.
// ---------------------------------------------------------------------------
__global__ __launch_bounds__(256) void passB_k(const unsigned* __restrict__ pairs,
                                               const int* __restrict__ cursor,
                                               int* __restrict__ offs,
                                               int* __restrict__ degcnt,
                                               float* __restrict__ dinv,
                                               int* __restrict__ csr) {
    __shared__ unsigned pk[CAPB];
    __shared__ int cnt[256];
    __shared__ int loff[256];
    __shared__ int sc[256];
    const int tid = threadIdx.x;
    const int b = blockIdx.x;
    const int p0 = b * CAPB;
    const int np = cursor[b] - p0;
    const int nb0 = b << BSH;
    const int nnode = (NN - nb0 < 256) ? (NN - nb0) : 256;

    cnt[tid] = 0;
    __syncthreads();
    for (int i = tid; i < np; i += 256) {
        const unsigned p = pairs[p0 + i];
        pk[i] = p;
        atomicAdd(&cnt[p >> 17], 1);
    }
    __syncthreads();
    sc[tid] = cnt[tid];
    __syncthreads();
    for (int off = 1; off < 256; off <<= 1) {
        int t = (tid >= off) ? sc[tid - off] : 0;
        __syncthreads();
        sc[tid] += t;
        __syncthreads();
    }
    const int ex = sc[tid] - cnt[tid];
    loff[tid] = ex;
    if (tid < nnode) {
        const int node = nb0 + tid;
        offs[node] = p0 + ex;
        degcnt[node] = cnt[tid];
        dinv[node] = 1.0f / sqrtf((float)(cnt[tid] + 1));
    }
    __syncthreads();
    cnt[tid] = 0;
    __syncthreads();
    for (int i = tid; i < np; i += 256) {
        const unsigned p = pk[i];
        const int dl = (int)(p >> 17);
        const int r = atomicAdd(&cnt[dl], 1);
        csr[p0 + loff[dl] + r] = (int)(p & 0x1FFFFu);
    }
}

// ---------------------------------------------------------------------------
// f32 GEMM: C[M,128] = A[M,128] @ B[128,128], C written as packed bf16.
// ---------------------------------------------------------------------------
static __device__ __forceinline__ float sani(float v) {
    if (isnan(v)) return 0.0f;
    if (isinf(v)) return v > 0.0f ? 1e6f : -1e6f;
    return v;
}

template <bool SANITIZE>
__global__ __launch_bounds__(256) void gemm128_k(const float* __restrict__ A,
                                                 const float* __restrict__ B,
                                                 unsigned* __restrict__ C, int M) {
    __shared__ float As[16][68];
    __shared__ float Bs[16][132];
    const int tid = threadIdx.x;
    const int tx = tid & 15;
    const int ty = tid >> 4;
    const int row0 = blockIdx.x * 64;

    float acc[4][8];
#pragma unroll
    for (int i = 0; i < 4; ++i)
#pragma unroll
        for (int j = 0; j < 8; ++j) acc[i][j] = 0.0f;

    const int lrow = tid >> 2;
    const int lseg = tid & 3;
    const int arow = row0 + lrow;

    for (int kt = 0; kt < 8; ++kt) {
        float4 av = make_float4(0.f, 0.f, 0.f, 0.f);
        if (arow < M) {
            av = *(const float4*)(A + (size_t)arow * HH + kt * 16 + lseg * 4);
            if (SANITIZE) {
                av.x = sani(av.x); av.y = sani(av.y);
                av.z = sani(av.z); av.w = sani(av.w);
            }
        }
        const int f0 = tid,        k0 = f0 >> 5, c0 = (f0 & 31) * 4;
        const int f1 = tid + 256,  k1 = f1 >> 5, c1 = (f1 & 31) * 4;
        const float4 bv0 = *(const float4*)(B + (size_t)(kt * 16 + k0) * HH + c0);
        const float4 bv1 = *(const float4*)(B + (size_t)(kt * 16 + k1) * HH + c1);

        __syncthreads();
        As[lseg * 4 + 0][lrow] = av.x;
        As[lseg * 4 + 1][lrow] = av.y;
        As[lseg * 4 + 2][lrow] = av.z;
        As[lseg * 4 + 3][lrow] = av.w;
        *(float4*)&Bs[k0][c0] = bv0;
        *(float4*)&Bs[k1][c1] = bv1;
        __syncthreads();

#pragma unroll
        for (int k = 0; k < 16; ++k) {
            const float4 a  = *(const float4*)&As[k][ty * 4];
            const float4 b0 = *(const float4*)&Bs[k][tx * 8];
            const float4 b1 = *(const float4*)&Bs[k][tx * 8 + 4];
            const float aa[4] = {a.x, a.y, a.z, a.w};
            const float bb[8] = {b0.x, b0.y, b0.z, b0.w, b1.x, b1.y, b1.z, b1.w};
#pragma unroll
            for (int i = 0; i < 4; ++i)
#pragma unroll
                for (int j = 0; j < 8; ++j) acc[i][j] += aa[i] * bb[j];
        }
    }

#pragma unroll
    for (int i = 0; i < 4; ++i) {
        const int r = row0 + ty * 4 + i;
        if (r < M) {
            // row r in bf16: 64 uints per row; this thread covers uints tx*4..tx*4+3
            uint4 o;
            o.x = packbf(acc[i][0], acc[i][1]);
            o.y = packbf(acc[i][2], acc[i][3]);
            o.z = packbf(acc[i][4], acc[i][5]);
            o.w = packbf(acc[i][6], acc[i][7]);
            *(uint4*)(C + (size_t)r * 64 + tx * 4) = o;
        }
    }
}

// ---------------------------------------------------------------------------
// Fused aggregate + bias + BN(eval) + ReLU, bf16 gather source.
// One wave per node. 16 lanes per row slice: lane group cg = lane&15 owns
// channels cg*8..cg*8+7 (uint4 = 16 B of bf16); sub = lane>>4 picks edge
// i+sub; 8 edges in flight per iteration; shfl_xor(16/32) reduction.
// ---------------------------------------------------------------------------
__global__ __launch_bounds__(256) void aggregate_k(
    const unsigned* __restrict__ hpre, const int* __restrict__ csr,
    const int* __restrict__ offs, const int* __restrict__ cnt,
    const float* __restrict__ dinv,
    const float* __restrict__ bias, const float* __restrict__ gamma,
    const float* __restrict__ beta, const float* __restrict__ mean,
    const float* __restrict__ var, float* __restrict__ xout) {
    const int v = __builtin_amdgcn_readfirstlane(blockIdx.x * 4 + (threadIdx.x >> 6));
    const int lane = threadIdx.x & 63;
    const int cg = lane & 15;
    const int sub = lane >> 4;
    const int c8 = cg * 8;

    // per-channel BN scale/shift: y = agg*sc + sh
    float scv[8], shv[8];
    {
        const float4 ga = *(const float4*)(gamma + c8), gb = *(const float4*)(gamma + c8 + 4);
        const float4 va = *(const float4*)(var + c8),   vb = *(const float4*)(var + c8 + 4);
        const float4 ba = *(const float4*)(bias + c8),  bb = *(const float4*)(bias + c8 + 4);
        const float4 ma = *(const float4*)(mean + c8),  mb = *(const float4*)(mean + c8 + 4);
        const float4 ea = *(const float4*)(beta + c8),  eb = *(const float4*)(beta + c8 + 4);
        const float g[8] = {ga.x, ga.y, ga.z, ga.w, gb.x, gb.y, gb.z, gb.w};
        const float vv[8] = {va.x, va.y, va.z, va.w, vb.x, vb.y, vb.z, vb.w};
        const float bi[8] = {ba.x, ba.y, ba.z, ba.w, bb.x, bb.y, bb.z, bb.w};
        const float mm[8] = {ma.x, ma.y, ma.z, ma.w, mb.x, mb.y, mb.z, mb.w};
        const float be[8] = {ea.x, ea.y, ea.z, ea.w, eb.x, eb.y, eb.z, eb.w};
#pragma unroll
        for (int j = 0; j < 8; ++j) {
            scv[j] = g[j] / sqrtf(vv[j] + 1e-5f);
            shv[j] = (bi[j] - mm[j]) * scv[j] + be[j];
        }
    }

    const float dv = dinv[v];
    const int start = offs[v];
    const int n = cnt[v];
    const uint4* __restrict__ hq = (const uint4*)hpre;   // 16 uint4 per row

    float acc[8];
#pragma unroll
    for (int j = 0; j < 8; ++j) acc[j] = 0.0f;

    for (int i = 0; i < n; i += 8) {
        const int e0 = i + sub, e1 = i + 4 + sub;
        float w0 = 0.0f, w1 = 0.0f;
        uint4 r0 = make_uint4(0, 0, 0, 0), r1 = make_uint4(0, 0, 0, 0);
        if (e0 < n) {
            const int s0 = csr[start + e0];
            w0 = dinv[s0];
            r0 = hq[(size_t)s0 * 16 + cg];
        }
        if (e1 < n) {
            const int s1 = csr[start + e1];
            w1 = dinv[s1];
            r1 = hq[(size_t)s1 * 16 + cg];
        }
        acc[0] += w0 * bflo(r0.x) + w1 * bflo(r1.x);
        acc[1] += w0 * bfhi(r0.x) + w1 * bfhi(r1.x);
        acc[2] += w0 * bflo(r0.y) + w1 * bflo(r1.y);
        acc[3] += w0 * bfhi(r0.y) + w1 * bfhi(r1.y);
        acc[4] += w0 * bflo(r0.z) + w1 * bflo(r1.z);
        acc[5] += w0 * bfhi(r0.z) + w1 * bfhi(r1.z);
        acc[6] += w0 * bflo(r0.w) + w1 * bflo(r1.w);
        acc[7] += w0 * bfhi(r0.w) + w1 * bfhi(r1.w);
    }

#pragma unroll
    for (int j = 0; j < 8; ++j) {
        acc[j] += __shfl_xor(acc[j], 16);
        acc[j] += __shfl_xor(acc[j], 32);
    }

    if (sub == 0) {
        const uint4 rs = hq[(size_t)v * 16 + cg];
        const float dv2 = dv * dv;
        float y[8];
        const float s0 = dv * acc[0] + dv2 * bflo(rs.x);
        const float s1 = dv * acc[1] + dv2 * bfhi(rs.x);
        const float s2 = dv * acc[2] + dv2 * bflo(rs.y);
        const float s3 = dv * acc[3] + dv2 * bfhi(rs.y);
        const float s4 = dv * acc[4] + dv2 * bflo(rs.z);
        const float s5 = dv * acc[5] + dv2 * bfhi(rs.z);
        const float s6 = dv * acc[6] + dv2 * bflo(rs.w);
        const float s7 = dv * acc[7] + dv2 * bfhi(rs.w);
        y[0] = fmaxf(s0 * scv[0] + shv[0], 0.0f);
        y[1] = fmaxf(s1 * scv[1] + shv[1], 0.0f);
        y[2] = fmaxf(s2 * scv[2] + shv[2], 0.0f);
        y[3] = fmaxf(s3 * scv[3] + shv[3], 0.0f);
        y[4] = fmaxf(s4 * scv[4] + shv[4], 0.0f);
        y[5] = fmaxf(s5 * scv[5] + shv[5], 0.0f);
        y[6] = fmaxf(s6 * scv[6] + shv[6], 0.0f);
        y[7] = fmaxf(s7 * scv[7] + shv[7], 0.0f);
        float4* o = (float4*)(xout + (size_t)v * HH + c8);
        o[0] = make_float4(y[0], y[1], y[2], y[3]);
        o[1] = make_float4(y[4], y[5], y[6], y[7]);
    }
}

// ---------------------------------------------------------------------------
// Global mean pool (batch sorted) + 2-layer FC head, one block per graph.
// ---------------------------------------------------------------------------
__global__ __launch_bounds__(128) void pool_head_k(
    const float* __restrict__ x, const int* __restrict__ batch,
    const int* __restrict__ flags,
    const float* __restrict__ fw1, const float* __restrict__ fb1,
    const float* __restrict__ fw2, const float* __restrict__ fb2,
    float* __restrict__ out) {
    __shared__ float pooled[128];
    __shared__ float hid[64];
    const int g = blockIdx.x;
    const int tid = threadIdx.x;
    const bool b64 = flags[1] != 0;

    int lo = 0, hi = NN;
    while (lo < hi) {
        const int mid = (lo + hi) >> 1;
        const int bv = b64 ? batch[2 * mid] : batch[mid];
        if (bv < g) lo = mid + 1; else hi = mid;
    }
    const int beg = lo;
    lo = beg; hi = NN;
    while (lo < hi) {
        const int mid = (lo + hi) >> 1;
        const int bv = b64 ? batch[2 * mid] : batch[mid];
        if (bv < g + 1) lo = mid + 1; else hi = mid;
    }
    const int end = lo;
    const int cntn = end - beg;

    float s0 = 0.f, s1 = 0.f, s2 = 0.f, s3 = 0.f;
    int i = beg;
    for (; i + 4 <= end; i += 4) {
        s0 += x[(size_t)(i + 0) * HH + tid];
        s1 += x[(size_t)(i + 1) * HH + tid];
        s2 += x[(size_t)(i + 2) * HH + tid];
        s3 += x[(size_t)(i + 3) * HH + tid];
    }
    for (; i < end; ++i) s0 += x[(size_t)i * HH + tid];
    const float s = (s0 + s1) + (s2 + s3);
    pooled[tid] = s / (float)(cntn > 0 ? cntn : 1);
    __syncthreads();

    if (tid < 64) {
        float a = fb1[tid];
#pragma unroll 4
        for (int k = 0; k < 128; ++k) a += pooled[k] * fw1[k * 64 + tid];
        hid[tid] = fmaxf(a, 0.0f);
    }
    __syncthreads();
    if (tid < 10) {
        float a = fb2[tid];
#pragma unroll
        for (int k = 0; k < 64; ++k) a += hid[k] * fw2[k * 10 + tid];
        out[g * 10 + tid] = a;
    }
}

// ---------------------------------------------------------------------------
// launch
// ---------------------------------------------------------------------------
extern "C" void kernel_launch(void* const* d_in, const int* in_sizes, int n_in,
                              void* d_out, int out_size, void* d_ws, size_t ws_size,
                              hipStream_t stream) {
    const float* x_in  = (const float*)d_in[0];
    const int*   ei    = (const int*)d_in[1];
    const int*   batch = (const int*)d_in[2];
    const float* w1 = (const float*)d_in[3];
    const float* b1 = (const float*)d_in[4];
    const float* w2 = (const float*)d_in[5];
    const float* b2 = (const float*)d_in[6];
    const float* w3 = (const float*)d_in[7];
    const float* b3 = (const float*)d_in[8];
    const float* g1 = (const float*)d_in[9];
    const float* be1 = (const float*)d_in[10];
    const float* m1 = (const float*)d_in[11];
    const float* v1 = (const float*)d_in[12];
    const float* g2 = (const float*)d_in[13];
    const float* be2 = (const float*)d_in[14];
    const float* m2 = (const float*)d_in[15];
    const float* v2 = (const float*)d_in[16];
    const float* g3 = (const float*)d_in[17];
    const float* be3 = (const float*)d_in[18];
    const float* m3 = (const float*)d_in[19];
    const float* v3 = (const float*)d_in[20];
    const float* fw1 = (const float*)d_in[21];
    const float* fb1 = (const float*)d_in[22];
    const float* fw2 = (const float*)d_in[23];
    const float* fb2 = (const float*)d_in[24];
    float* out = (float*)d_out;

    size_t off = 0;
    char* base = (char*)d_ws;
    auto alloc = [&](size_t bytes) -> void* {
        void* p = base + off;
        off += (bytes + 255) & ~(size_t)255;
        return p;
    };
    int*      degcnt = (int*)alloc((size_t)NN * 4);
    float*    dinv   = (float*)alloc((size_t)NN * 4);
    int*      offs   = (int*)alloc((size_t)NN * 4);
    int*      cursor = (int*)alloc((size_t)NBK * 4);
    int*      flags  = (int*)alloc(256);
    int*      csr    = (int*)alloc((size_t)NBK * CAPB * 4);
    unsigned* pairs  = (unsigned*)alloc((size_t)NBK * CAPB * 4);
    float*    bufx   = (float*)alloc((size_t)NN * HH * 4);
    unsigned* hpre   = (unsigned*)alloc((size_t)NN * (HH / 2) * 4);  // bf16 x2 packed
    if (off > ws_size) return;

    detect_k<<<1, 64, 0, stream>>>(ei, batch, flags);
    cursinit_k<<<1, 512, 0, stream>>>(cursor);
    passA_k<<<PASSA_WG, 256, 0, stream>>>(ei, flags, cursor, pairs);
    passB_k<<<NBK, 256, 0, stream>>>(pairs, cursor, offs, degcnt, dinv, csr);

    const int ggrid = (NN + 63) / 64;          // 1563
    const int agrid = NN / 4;                  // 25000

    gemm128_k<true><<<ggrid, 256, 0, stream>>>(x_in, w1, hpre, NN);
    aggregate_k<<<agrid, 256, 0, stream>>>(hpre, csr, offs, degcnt, dinv,
                                           b1, g1, be1, m1, v1, bufx);
    gemm128_k<false><<<ggrid, 256, 0, stream>>>(bufx, w2, hpre, NN);
    aggregate_k<<<agrid, 256, 0, stream>>>(hpre, csr, offs, degcnt, dinv,
                                           b2, g2, be2, m2, v2, bufx);
    gemm128_k<false><<<ggrid, 256, 0, stream>>>(bufx, w3, hpre, NN);
    aggregate_k<<<agrid, 256, 0, stream>>>(hpre, csr, offs, degcnt, dinv,
                                           b3, g3, be3, m3, v3, bufx);

    pool_head_k<<<GG, 128, 0, stream>>>(bufx, batch, flags,
                                        fw1, fb1, fw2, fb2, out);
}

// Round 4
// 583.223 us; speedup vs baseline: 1.5150x; 1.1581x over previous
//
#include <hip/hip_runtime.h>
#include <math.h>

#define NN 100000
#define EE 1600000
#define GG 256
#define HH 128
#define BSH 8                 /* 256 nodes per bucket */
#define NBK 391               /* ceil(NN/256) */
#define PASSA_WG 391          /* ceil(EE/4096) */
#define CAPB 5120             /* fixed region capacity per bucket (mean 4092, +16 sigma) */

// ---------------------------------------------------------------------------
// bf16 helpers (RNE pack, cheap unpack)
// ---------------------------------------------------------------------------
static __device__ __forceinline__ unsigned bf16rne(float f) {
    const unsigned u = __float_as_uint(f);
    return (u + 0x7fffu + ((u >> 16) & 1u)) >> 16;
}
static __device__ __forceinline__ unsigned packbf(float a, float b) {
    return bf16rne(a) | (bf16rne(b) << 16);
}
static __device__ __forceinline__ float bflo(unsigned u) { return __uint_as_float(u << 16); }
static __device__ __forceinline__ float bfhi(unsigned u) { return __uint_as_float(u & 0xffff0000u); }

// ---------------------------------------------------------------------------
// dtype layout detection (int32 vs int64 device layout for edge_index/batch)
// ---------------------------------------------------------------------------
__global__ void detect_k(const int* __restrict__ ei, const int* __restrict__ batch,
                         int* __restrict__ flags) {
    if (threadIdx.x == 0 && blockIdx.x == 0) {
        int e64 = 1;
        for (int j = 0; j < 8; ++j) {
            if (ei[2 * EE - 1 - 2 * j] != 0) { e64 = 0; break; }
        }
        flags[0] = e64;
        flags[1] = (batch[NN - 1] == 0) ? 1 : 0;
    }
}

// cursor[b] = b*CAPB (fixed per-bucket region bases)
__global__ __launch_bounds__(512) void cursinit_k(int* __restrict__ cursor) {
    const int b = blockIdx.x * 512 + threadIdx.x;
    if (b < NBK) cursor[b] = b * CAPB;
}

// ---------------------------------------------------------------------------
// BN eval coefficients, hoisted: sc = g*rsqrt(v+eps), sh = (b-m)*sc + be.
// One launch for all 3 layers -> sc[3*128], sh[3*128].
// ---------------------------------------------------------------------------
__global__ void bnprep_k(const float* __restrict__ b1, const float* __restrict__ g1,
                         const float* __restrict__ be1, const float* __restrict__ m1,
                         const float* __restrict__ v1,
                         const float* __restrict__ b2, const float* __restrict__ g2,
                         const float* __restrict__ be2, const float* __restrict__ m2,
                         const float* __restrict__ v2,
                         const float* __restrict__ b3, const float* __restrict__ g3,
                         const float* __restrict__ be3, const float* __restrict__ m3,
                         const float* __restrict__ v3,
                         float* __restrict__ sc, float* __restrict__ sh) {
    const int c = threadIdx.x;
    float s;
    s = g1[c] / sqrtf(v1[c] + 1e-5f);
    sc[c] = s;           sh[c] = (b1[c] - m1[c]) * s + be1[c];
    s = g2[c] / sqrtf(v2[c] + 1e-5f);
    sc[128 + c] = s;     sh[128 + c] = (b2[c] - m2[c]) * s + be2[c];
    s = g3[c] / sqrtf(v3[c] + 1e-5f);
    sc[256 + c] = s;     sh[256 + c] = (b3[c] - m3[c]) * s + be3[c];
}

// ---------------------------------------------------------------------------
// pass A: bucket-grouped packed-pair scatter into fixed regions.
// packed = (dloc<<17) | src   (src < 2^17, dloc < 256)
// ---------------------------------------------------------------------------
__global__ __launch_bounds__(256) void passA_k(const int* __restrict__ ei,
                                               const int* __restrict__ flags,
                                               int* __restrict__ cursor,
                                               unsigned* __restrict__ pairs) {
    __shared__ int h[NBK];
    __shared__ int rbase[NBK];
    const int tid = threadIdx.x;
    for (int i = tid; i < NBK; i += 256) h[i] = 0;
    __syncthreads();
    const bool e64 = flags[0] != 0;
    const int base = blockIdx.x * 4096;
    int scache[16], dcache[16];
#pragma unroll
    for (int j = 0; j < 16; ++j) {
        const int e = base + j * 256 + tid;
        int s = -1, d = 0;
        if (e < EE) {
            s = e64 ? ei[2 * e] : ei[e];
            d = e64 ? ei[2 * (EE + e)] : ei[EE + e];
            atomicAdd(&h[d >> BSH], 1);
        }
        scache[j] = s; dcache[j] = d;
    }
    __syncthreads();
    for (int i = tid; i < NBK; i += 256) {
        const int c = h[i];
        rbase[i] = c ? atomicAdd(&cursor[i], c) : 0;
    }
    __syncthreads();
    for (int i = tid; i < NBK; i += 256) h[i] = 0;
    __syncthreads();
#pragma unroll
    for (int j = 0; j < 16; ++j) {
        const int s = scache[j];
        if (s >= 0) {
            const int d = dcache[j];
            const int b = d >> BSH;
            const int r = atomicAdd(&h[b], 1);
            pairs[rbase[b] + r] = ((unsigned)(d & 255) << 17) | (unsigned)s;
        }
    }
}

// ---------------------------------------------------------------------------
// pass B: one wg per bucket. Stage packed pairs in LDS, per-node count+scan
// -> offs/degcnt/dinv, LDS-ranked scatter into the bucket's CSR region.
// ---------------------------------------------------------------------------
__global__ __launch_bounds__(256) void passB_k(const unsigned* __restrict__ pairs,
                                               const int* __restrict__ cursor,
                                               int* __restrict__ offs,
                                               int* __restrict__ degcnt,
                                               float* __restrict__ dinv,
                                               int* __restrict__ csr) {
    __shared__ unsigned pk[CAPB];
    __shared__ int cnt[256];
    __shared__ int loff[256];
    __shared__ int sc[256];
    const int tid = threadIdx.x;
    const int b = blockIdx.x;
    const int p0 = b * CAPB;
    const int np = cursor[b] - p0;
    const int nb0 = b << BSH;
    const int nnode = (NN - nb0 < 256) ? (NN - nb0) : 256;

    cnt[tid] = 0;
    __syncthreads();
    for (int i = tid; i < np; i += 256) {
        const unsigned p = pairs[p0 + i];
        pk[i] = p;
        atomicAdd(&cnt[p >> 17], 1);
    }
    __syncthreads();
    sc[tid] = cnt[tid];
    __syncthreads();
    for (int off = 1; off < 256; off <<= 1) {
        int t = (tid >= off) ? sc[tid - off] : 0;
        __syncthreads();
        sc[tid] += t;
        __syncthreads();
    }
    const int ex = sc[tid] - cnt[tid];
    loff[tid] = ex;
    if (tid < nnode) {
        const int node = nb0 + tid;
        offs[node] = p0 + ex;
        degcnt[node] = cnt[tid];
        dinv[node] = 1.0f / sqrtf((float)(cnt[tid] + 1));
    }
    __syncthreads();
    cnt[tid] = 0;
    __syncthreads();
    for (int i = tid; i < np; i += 256) {
        const unsigned p = pk[i];
        const int dl = (int)(p >> 17);
        const int r = atomicAdd(&cnt[dl], 1);
        csr[p0 + loff[dl] + r] = (int)(p & 0x1FFFFu);
    }
}

// ---------------------------------------------------------------------------
// f32 GEMM: C[M,128] = A[M,128] @ B[128,128], C written as packed bf16.
// ---------------------------------------------------------------------------
static __device__ __forceinline__ float sani(float v) {
    if (isnan(v)) return 0.0f;
    if (isinf(v)) return v > 0.0f ? 1e6f : -1e6f;
    return v;
}

template <bool SANITIZE>
__global__ __launch_bounds__(256) void gemm128_k(const float* __restrict__ A,
                                                 const float* __restrict__ B,
                                                 unsigned* __restrict__ C, int M) {
    __shared__ float As[16][68];
    __shared__ float Bs[16][132];
    const int tid = threadIdx.x;
    const int tx = tid & 15;
    const int ty = tid >> 4;
    const int row0 = blockIdx.x * 64;

    float acc[4][8];
#pragma unroll
    for (int i = 0; i < 4; ++i)
#pragma unroll
        for (int j = 0; j < 8; ++j) acc[i][j] = 0.0f;

    const int lrow = tid >> 2;
    const int lseg = tid & 3;
    const int arow = row0 + lrow;

    for (int kt = 0; kt < 8; ++kt) {
        float4 av = make_float4(0.f, 0.f, 0.f, 0.f);
        if (arow < M) {
            av = *(const float4*)(A + (size_t)arow * HH + kt * 16 + lseg * 4);
            if (SANITIZE) {
                av.x = sani(av.x); av.y = sani(av.y);
                av.z = sani(av.z); av.w = sani(av.w);
            }
        }
        const int f0 = tid,        k0 = f0 >> 5, c0 = (f0 & 31) * 4;
        const int f1 = tid + 256,  k1 = f1 >> 5, c1 = (f1 & 31) * 4;
        const float4 bv0 = *(const float4*)(B + (size_t)(kt * 16 + k0) * HH + c0);
        const float4 bv1 = *(const float4*)(B + (size_t)(kt * 16 + k1) * HH + c1);

        __syncthreads();
        As[lseg * 4 + 0][lrow] = av.x;
        As[lseg * 4 + 1][lrow] = av.y;
        As[lseg * 4 + 2][lrow] = av.z;
        As[lseg * 4 + 3][lrow] = av.w;
        *(float4*)&Bs[k0][c0] = bv0;
        *(float4*)&Bs[k1][c1] = bv1;
        __syncthreads();

#pragma unroll
        for (int k = 0; k < 16; ++k) {
            const float4 a  = *(const float4*)&As[k][ty * 4];
            const float4 b0 = *(const float4*)&Bs[k][tx * 8];
            const float4 b1 = *(const float4*)&Bs[k][tx * 8 + 4];
            const float aa[4] = {a.x, a.y, a.z, a.w};
            const float bb[8] = {b0.x, b0.y, b0.z, b0.w, b1.x, b1.y, b1.z, b1.w};
#pragma unroll
            for (int i = 0; i < 4; ++i)
#pragma unroll
                for (int j = 0; j < 8; ++j) acc[i][j] += aa[i] * bb[j];
        }
    }

#pragma unroll
    for (int i = 0; i < 4; ++i) {
        const int r = row0 + ty * 4 + i;
        if (r < M) {
            uint4 o;
            o.x = packbf(acc[i][0], acc[i][1]);
            o.y = packbf(acc[i][2], acc[i][3]);
            o.z = packbf(acc[i][4], acc[i][5]);
            o.w = packbf(acc[i][6], acc[i][7]);
            *(uint4*)(C + (size_t)r * 64 + tx * 4) = o;
        }
    }
}

// ---------------------------------------------------------------------------
// Fused aggregate + bias + BN(eval) + ReLU, bf16 gather source.
// One wave per node; 16 lanes per row slice (lane cg owns channels cg*8..+7),
// sub = lane>>4 picks edge i + {0,4,8,12} + sub: 16 edges per iteration,
// 4 gathers in flight per lane. Invalid slots are index-clamped with zeroed
// weights (no exec-masked loads). BN coefficients precomputed (bnprep_k).
// ---------------------------------------------------------------------------
__global__ __launch_bounds__(256) void aggregate_k(
    const unsigned* __restrict__ hpre, const int* __restrict__ csr,
    const int* __restrict__ offs, const int* __restrict__ cnt,
    const float* __restrict__ dinv,
    const float* __restrict__ bnsc, const float* __restrict__ bnsh,
    float* __restrict__ xout) {
    const int v = __builtin_amdgcn_readfirstlane(blockIdx.x * 4 + (threadIdx.x >> 6));
    const int lane = threadIdx.x & 63;
    const int cg = lane & 15;
    const int sub = lane >> 4;
    const int c8 = cg * 8;

    const float dv = dinv[v];
    const int start = offs[v];
    const int n = cnt[v];
    const char* __restrict__ hb = (const char*)hpre;   // row = 256 B
    const unsigned cgo = (unsigned)(cg << 4);

    float acc[8];
#pragma unroll
    for (int j = 0; j < 8; ++j) acc[j] = 0.0f;

    for (int i = 0; i < n; i += 16) {
        const int e0 = i + sub, e1 = i + 4 + sub, e2 = i + 8 + sub, e3 = i + 12 + sub;
        const int nm1 = n - 1;
        const int s0 = csr[start + min(e0, nm1)];
        const int s1 = csr[start + min(e1, nm1)];
        const int s2 = csr[start + min(e2, nm1)];
        const int s3 = csr[start + min(e3, nm1)];
        const float w0 = (e0 < n) ? dinv[s0] : 0.0f;
        const float w1 = (e1 < n) ? dinv[s1] : 0.0f;
        const float w2 = (e2 < n) ? dinv[s2] : 0.0f;
        const float w3 = (e3 < n) ? dinv[s3] : 0.0f;
        const uint4 r0 = *(const uint4*)(hb + (((unsigned)s0 << 8) | cgo));
        const uint4 r1 = *(const uint4*)(hb + (((unsigned)s1 << 8) | cgo));
        const uint4 r2 = *(const uint4*)(hb + (((unsigned)s2 << 8) | cgo));
        const uint4 r3 = *(const uint4*)(hb + (((unsigned)s3 << 8) | cgo));

        acc[0] += w0 * bflo(r0.x); acc[1] += w0 * bfhi(r0.x);
        acc[2] += w0 * bflo(r0.y); acc[3] += w0 * bfhi(r0.y);
        acc[4] += w0 * bflo(r0.z); acc[5] += w0 * bfhi(r0.z);
        acc[6] += w0 * bflo(r0.w); acc[7] += w0 * bfhi(r0.w);
        acc[0] += w1 * bflo(r1.x); acc[1] += w1 * bfhi(r1.x);
        acc[2] += w1 * bflo(r1.y); acc[3] += w1 * bfhi(r1.y);
        acc[4] += w1 * bflo(r1.z); acc[5] += w1 * bfhi(r1.z);
        acc[6] += w1 * bflo(r1.w); acc[7] += w1 * bfhi(r1.w);
        acc[0] += w2 * bflo(r2.x); acc[1] += w2 * bfhi(r2.x);
        acc[2] += w2 * bflo(r2.y); acc[3] += w2 * bfhi(r2.y);
        acc[4] += w2 * bflo(r2.z); acc[5] += w2 * bfhi(r2.z);
        acc[6] += w2 * bflo(r2.w); acc[7] += w2 * bfhi(r2.w);
        acc[0] += w3 * bflo(r3.x); acc[1] += w3 * bfhi(r3.x);
        acc[2] += w3 * bflo(r3.y); acc[3] += w3 * bfhi(r3.y);
        acc[4] += w3 * bflo(r3.z); acc[5] += w3 * bfhi(r3.z);
        acc[6] += w3 * bflo(r3.w); acc[7] += w3 * bfhi(r3.w);
    }

#pragma unroll
    for (int j = 0; j < 8; ++j) {
        acc[j] += __shfl_xor(acc[j], 16);
        acc[j] += __shfl_xor(acc[j], 32);
    }

    if (sub == 0) {
        const float4 sca = *(const float4*)(bnsc + c8);
        const float4 scb = *(const float4*)(bnsc + c8 + 4);
        const float4 sha = *(const float4*)(bnsh + c8);
        const float4 shb = *(const float4*)(bnsh + c8 + 4);
        const uint4 rs = *(const uint4*)(hb + (((unsigned)v << 8) | cgo));
        const float dv2 = dv * dv;
        const float s0 = dv * acc[0] + dv2 * bflo(rs.x);
        const float s1 = dv * acc[1] + dv2 * bfhi(rs.x);
        const float s2 = dv * acc[2] + dv2 * bflo(rs.y);
        const float s3 = dv * acc[3] + dv2 * bfhi(rs.y);
        const float s4 = dv * acc[4] + dv2 * bflo(rs.z);
        const float s5 = dv * acc[5] + dv2 * bfhi(rs.z);
        const float s6 = dv * acc[6] + dv2 * bflo(rs.w);
        const float s7 = dv * acc[7] + dv2 * bfhi(rs.w);
        float4* o = (float4*)(xout + (size_t)v * HH + c8);
        o[0] = make_float4(fmaxf(s0 * sca.x + sha.x, 0.0f),
                           fmaxf(s1 * sca.y + sha.y, 0.0f),
                           fmaxf(s2 * sca.z + sha.z, 0.0f),
                           fmaxf(s3 * sca.w + sha.w, 0.0f));
        o[1] = make_float4(fmaxf(s4 * scb.x + shb.x, 0.0f),
                           fmaxf(s5 * scb.y + shb.y, 0.0f),
                           fmaxf(s6 * scb.z + shb.z, 0.0f),
                           fmaxf(s7 * scb.w + shb.w, 0.0f));
    }
}

// ---------------------------------------------------------------------------
// Global mean pool (batch sorted) + 2-layer FC head, one block per graph.
// ---------------------------------------------------------------------------
__global__ __launch_bounds__(128) void pool_head_k(
    const float* __restrict__ x, const int* __restrict__ batch,
    const int* __restrict__ flags,
    const float* __restrict__ fw1, const float* __restrict__ fb1,
    const float* __restrict__ fw2, const float* __restrict__ fb2,
    float* __restrict__ out) {
    __shared__ float pooled[128];
    __shared__ float hid[64];
    const int g = blockIdx.x;
    const int tid = threadIdx.x;
    const bool b64 = flags[1] != 0;

    int lo = 0, hi = NN;
    while (lo < hi) {
        const int mid = (lo + hi) >> 1;
        const int bv = b64 ? batch[2 * mid] : batch[mid];
        if (bv < g) lo = mid + 1; else hi = mid;
    }
    const int beg = lo;
    lo = beg; hi = NN;
    while (lo < hi) {
        const int mid = (lo + hi) >> 1;
        const int bv = b64 ? batch[2 * mid] : batch[mid];
        if (bv < g + 1) lo = mid + 1; else hi = mid;
    }
    const int end = lo;
    const int cntn = end - beg;

    float s0 = 0.f, s1 = 0.f, s2 = 0.f, s3 = 0.f;
    int i = beg;
    for (; i + 4 <= end; i += 4) {
        s0 += x[(size_t)(i + 0) * HH + tid];
        s1 += x[(size_t)(i + 1) * HH + tid];
        s2 += x[(size_t)(i + 2) * HH + tid];
        s3 += x[(size_t)(i + 3) * HH + tid];
    }
    for (; i < end; ++i) s0 += x[(size_t)i * HH + tid];
    const float s = (s0 + s1) + (s2 + s3);
    pooled[tid] = s / (float)(cntn > 0 ? cntn : 1);
    __syncthreads();

    if (tid < 64) {
        float a = fb1[tid];
#pragma unroll 4
        for (int k = 0; k < 128; ++k) a += pooled[k] * fw1[k * 64 + tid];
        hid[tid] = fmaxf(a, 0.0f);
    }
    __syncthreads();
    if (tid < 10) {
        float a = fb2[tid];
#pragma unroll
        for (int k = 0; k < 64; ++k) a += hid[k] * fw2[k * 10 + tid];
        out[g * 10 + tid] = a;
    }
}

// ---------------------------------------------------------------------------
// launch
// ---------------------------------------------------------------------------
extern "C" void kernel_launch(void* const* d_in, const int* in_sizes, int n_in,
                              void* d_out, int out_size, void* d_ws, size_t ws_size,
                              hipStream_t stream) {
    const float* x_in  = (const float*)d_in[0];
    const int*   ei    = (const int*)d_in[1];
    const int*   batch = (const int*)d_in[2];
    const float* w1 = (const float*)d_in[3];
    const float* b1 = (const float*)d_in[4];
    const float* w2 = (const float*)d_in[5];
    const float* b2 = (const float*)d_in[6];
    const float* w3 = (const float*)d_in[7];
    const float* b3 = (const float*)d_in[8];
    const float* g1 = (const float*)d_in[9];
    const float* be1 = (const float*)d_in[10];
    const float* m1 = (const float*)d_in[11];
    const float* v1 = (const float*)d_in[12];
    const float* g2 = (const float*)d_in[13];
    const float* be2 = (const float*)d_in[14];
    const float* m2 = (const float*)d_in[15];
    const float* v2 = (const float*)d_in[16];
    const float* g3 = (const float*)d_in[17];
    const float* be3 = (const float*)d_in[18];
    const float* m3 = (const float*)d_in[19];
    const float* v3 = (const float*)d_in[20];
    const float* fw1 = (const float*)d_in[21];
    const float* fb1 = (const float*)d_in[22];
    const float* fw2 = (const float*)d_in[23];
    const float* fb2 = (const float*)d_in[24];
    float* out = (float*)d_out;

    size_t off = 0;
    char* base = (char*)d_ws;
    auto alloc = [&](size_t bytes) -> void* {
        void* p = base + off;
        off += (bytes + 255) & ~(size_t)255;
        return p;
    };
    int*      degcnt = (int*)alloc((size_t)NN * 4);
    float*    dinv   = (float*)alloc((size_t)NN * 4);
    int*      offs   = (int*)alloc((size_t)NN * 4);
    int*      cursor = (int*)alloc((size_t)NBK * 4);
    int*      flags  = (int*)alloc(256);
    float*    bnsc   = (float*)alloc(3 * 128 * 4);
    float*    bnsh   = (float*)alloc(3 * 128 * 4);
    int*      csr    = (int*)alloc((size_t)NBK * CAPB * 4);
    unsigned* pairs  = (unsigned*)alloc((size_t)NBK * CAPB * 4);
    float*    bufx   = (float*)alloc((size_t)NN * HH * 4);
    unsigned* hpre   = (unsigned*)alloc((size_t)NN * (HH / 2) * 4);  // bf16 x2 packed
    if (off > ws_size) return;

    detect_k<<<1, 64, 0, stream>>>(ei, batch, flags);
    cursinit_k<<<1, 512, 0, stream>>>(cursor);
    bnprep_k<<<1, 128, 0, stream>>>(b1, g1, be1, m1, v1,
                                    b2, g2, be2, m2, v2,
                                    b3, g3, be3, m3, v3, bnsc, bnsh);
    passA_k<<<PASSA_WG, 256, 0, stream>>>(ei, flags, cursor, pairs);
    passB_k<<<NBK, 256, 0, stream>>>(pairs, cursor, offs, degcnt, dinv, csr);

    const int ggrid = (NN + 63) / 64;          // 1563
    const int agrid = NN / 4;                  // 25000

    gemm128_k<true><<<ggrid, 256, 0, stream>>>(x_in, w1, hpre, NN);
    aggregate_k<<<agrid, 256, 0, stream>>>(hpre, csr, offs, degcnt, dinv,
                                           bnsc, bnsh, bufx);
    gemm128_k<false><<<ggrid, 256, 0, stream>>>(bufx, w2, hpre, NN);
    aggregate_k<<<agrid, 256, 0, stream>>>(hpre, csr, offs, degcnt, dinv,
                                           bnsc + 128, bnsh + 128, bufx);
    gemm128_k<false><<<ggrid, 256, 0, stream>>>(bufx, w3, hpre, NN);
    aggregate_k<<<agrid, 256, 0, stream>>>(hpre, csr, offs, degcnt, dinv,
                                           bnsc + 256, bnsh + 256, bufx);

    pool_head_k<<<GG, 128, 0, stream>>>(bufx, batch, flags,
                                        fw1, fb1, fw2, fb2, out);
}

// Round 6
// 493.413 us; speedup vs baseline: 1.7908x; 1.1820x over previous
//
#include <hip/hip_runtime.h>
#include <math.h>

#define NN 100000
#define EE 1600000
#define GG 256
#define HH 128
#define BSH 8                 /* 256 nodes per bucket */
#define NBK 391               /* ceil(NN/256) */
#define PASSA_WG 391          /* ceil(EE/4096) */
#define CAPB 5120             /* fixed region capacity per bucket (mean 4092, +16 sigma) */

typedef __attribute__((ext_vector_type(8))) short short8;   // 8 bf16 (4 VGPRs)
typedef __attribute__((ext_vector_type(4))) float f32x4;    // MFMA acc

union U4S8 { uint4 u; short8 s; };

// ---------------------------------------------------------------------------
// bf16 helpers (RNE pack, cheap unpack)
// ---------------------------------------------------------------------------
static __device__ __forceinline__ unsigned bf16rne(float f) {
    const unsigned u = __float_as_uint(f);
    return (u + 0x7fffu + ((u >> 16) & 1u)) >> 16;
}
static __device__ __forceinline__ unsigned packbf(float a, float b) {
    return bf16rne(a) | (bf16rne(b) << 16);
}
static __device__ __forceinline__ float bflo(unsigned u) { return __uint_as_float(u << 16); }
static __device__ __forceinline__ float bfhi(unsigned u) { return __uint_as_float(u & 0xffff0000u); }

// ---------------------------------------------------------------------------
// dtype layout detection (int32 vs int64 device layout for edge_index/batch)
// ---------------------------------------------------------------------------
__global__ void detect_k(const int* __restrict__ ei, const int* __restrict__ batch,
                         int* __restrict__ flags) {
    if (threadIdx.x == 0 && blockIdx.x == 0) {
        int e64 = 1;
        for (int j = 0; j < 8; ++j) {
            if (ei[2 * EE - 1 - 2 * j] != 0) { e64 = 0; break; }
        }
        flags[0] = e64;
        flags[1] = (batch[NN - 1] == 0) ? 1 : 0;
    }
}

// cursor[b] = b*CAPB (fixed per-bucket region bases)
__global__ __launch_bounds__(512) void cursinit_k(int* __restrict__ cursor) {
    const int b = blockIdx.x * 512 + threadIdx.x;
    if (b < NBK) cursor[b] = b * CAPB;
}

// ---------------------------------------------------------------------------
// BN eval coefficients, hoisted (all 3 layers).
// ---------------------------------------------------------------------------
__global__ void bnprep_k(const float* __restrict__ b1, const float* __restrict__ g1,
                         const float* __restrict__ be1, const float* __restrict__ m1,
                         const float* __restrict__ v1,
                         const float* __restrict__ b2, const float* __restrict__ g2,
                         const float* __restrict__ be2, const float* __restrict__ m2,
                         const float* __restrict__ v2,
                         const float* __restrict__ b3, const float* __restrict__ g3,
                         const float* __restrict__ be3, const float* __restrict__ m3,
                         const float* __restrict__ v3,
                         float* __restrict__ sc, float* __restrict__ sh) {
    const int c = threadIdx.x;
    float s;
    s = g1[c] / sqrtf(v1[c] + 1e-5f);
    sc[c] = s;           sh[c] = (b1[c] - m1[c]) * s + be1[c];
    s = g2[c] / sqrtf(v2[c] + 1e-5f);
    sc[128 + c] = s;     sh[128 + c] = (b2[c] - m2[c]) * s + be2[c];
    s = g3[c] / sqrtf(v3[c] + 1e-5f);
    sc[256 + c] = s;     sh[256 + c] = (b3[c] - m3[c]) * s + be3[c];
}

// ---------------------------------------------------------------------------
// Weights -> bf16 B^T[n][k] (packed 2 bf16/uint, 64 uints per n-row), x3.
// ---------------------------------------------------------------------------
__global__ __launch_bounds__(256) void wprep_k(const float* __restrict__ w1,
                                               const float* __restrict__ w2,
                                               const float* __restrict__ w3,
                                               unsigned* __restrict__ bt) {
    const int id = blockIdx.x * 256 + threadIdx.x;   // 3*8192 total
    if (id >= 3 * 8192) return;
    const int w = id >> 13;
    const int rem = id & 8191;
    const int n = rem >> 6;
    const int kk = rem & 63;                          // k-pair
    const float* W = (w == 0) ? w1 : (w == 1) ? w2 : w3;
    bt[id] = packbf(W[(2 * kk) * HH + n], W[(2 * kk + 1) * HH + n]);
}

// ---------------------------------------------------------------------------
// pass A: bucket-grouped packed-pair scatter into fixed regions.
// packed = (dloc<<17) | src
// ---------------------------------------------------------------------------
__global__ __launch_bounds__(256) void passA_k(const int* __restrict__ ei,
                                               const int* __restrict__ flags,
                                               int* __restrict__ cursor,
                                               unsigned* __restrict__ pairs) {
    __shared__ int h[NBK];
    __shared__ int rbase[NBK];
    const int tid = threadIdx.x;
    for (int i = tid; i < NBK; i += 256) h[i] = 0;
    __syncthreads();
    const bool e64 = flags[0] != 0;
    const int base = blockIdx.x * 4096;
    int scache[16], dcache[16];
#pragma unroll
    for (int j = 0; j < 16; ++j) {
        const int e = base + j * 256 + tid;
        int s = -1, d = 0;
        if (e < EE) {
            s = e64 ? ei[2 * e] : ei[e];
            d = e64 ? ei[2 * (EE + e)] : ei[EE + e];
            atomicAdd(&h[d >> BSH], 1);
        }
        scache[j] = s; dcache[j] = d;
    }
    __syncthreads();
    for (int i = tid; i < NBK; i += 256) {
        const int c = h[i];
        rbase[i] = c ? atomicAdd(&cursor[i], c) : 0;
    }
    __syncthreads();
    for (int i = tid; i < NBK; i += 256) h[i] = 0;
    __syncthreads();
#pragma unroll
    for (int j = 0; j < 16; ++j) {
        const int s = scache[j];
        if (s >= 0) {
            const int d = dcache[j];
            const int b = d >> BSH;
            const int r = atomicAdd(&h[b], 1);
            pairs[rbase[b] + r] = ((unsigned)(d & 255) << 17) | (unsigned)s;
        }
    }
}

// ---------------------------------------------------------------------------
// pass B: one wg per bucket -> offs/degcnt/dinv + bucketed CSR.
// ---------------------------------------------------------------------------
__global__ __launch_bounds__(256) void passB_k(const unsigned* __restrict__ pairs,
                                               const int* __restrict__ cursor,
                                               int* __restrict__ offs,
                                               int* __restrict__ degcnt,
                                               float* __restrict__ dinv,
                                               int* __restrict__ csr) {
    __shared__ unsigned pk[CAPB];
    __shared__ int cnt[256];
    __shared__ int loff[256];
    __shared__ int sc[256];
    const int tid = threadIdx.x;
    const int b = blockIdx.x;
    const int p0 = b * CAPB;
    const int np = cursor[b] - p0;
    const int nb0 = b << BSH;
    const int nnode = (NN - nb0 < 256) ? (NN - nb0) : 256;

    cnt[tid] = 0;
    __syncthreads();
    for (int i = tid; i < np; i += 256) {
        const unsigned p = pairs[p0 + i];
        pk[i] = p;
        atomicAdd(&cnt[p >> 17], 1);
    }
    __syncthreads();
    sc[tid] = cnt[tid];
    __syncthreads();
    for (int off = 1; off < 256; off <<= 1) {
        int t = (tid >= off) ? sc[tid - off] : 0;
        __syncthreads();
        sc[tid] += t;
        __syncthreads();
    }
    const int ex = sc[tid] - cnt[tid];
    loff[tid] = ex;
    if (tid < nnode) {
        const int node = nb0 + tid;
        offs[node] = p0 + ex;
        degcnt[node] = cnt[tid];
        dinv[node] = 1.0f / sqrtf((float)(cnt[tid] + 1));
    }
    __syncthreads();
    cnt[tid] = 0;
    __syncthreads();
    for (int i = tid; i < np; i += 256) {
        const unsigned p = pk[i];
        const int dl = (int)(p >> 17);
        const int r = atomicAdd(&cnt[dl], 1);
        csr[p0 + loff[dl] + r] = (int)(p & 0x1FFFFu);
    }
}

// ---------------------------------------------------------------------------
// MFMA bf16 GEMM: C[M,128](bf16) = A[M,128] @ B[128,128], B given as
// bf16 B^T[n][k]. Block = 256 thr = 4 waves; wave = 16-row strip, 8 C-tiles
// of 16x16, K = 4 steps of 32 (v_mfma_f32_16x16x32_bf16).
// LDS: B^T staged at 68-uint row stride (16B-aligned, structural-min bank
// phasing); after a barrier the same LDS is reused to stage C (f32) for
// packed bf16 uint4 global stores.
// ---------------------------------------------------------------------------
static __device__ __forceinline__ float sani(float v) {
    if (isnan(v)) return 0.0f;
    if (isinf(v)) return v > 0.0f ? 1e6f : -1e6f;
    return v;
}

template <bool AF32>
__global__ __launch_bounds__(256) void gemm_mfma_k(const float* __restrict__ Af,
                                                   const unsigned* __restrict__ Abf,
                                                   const unsigned* __restrict__ btg,
                                                   unsigned* __restrict__ C, int M) {
    __shared__ unsigned lds_u[8704];   // 34816 B: B^T[128][68 uints], then C-staging
    const int tid = threadIdx.x;
    const int wave = tid >> 6;
    const int lane = tid & 63;
    const int nl = lane & 15;          // n within tile / m-row of A
    const int q = lane >> 4;           // k-quad

    // stage B^T: 128 rows x 64 uints (btg) -> LDS rows of 68 uints
    {
        const uint4* __restrict__ bg4 = (const uint4*)btg;
        for (int i = tid; i < 2048; i += 256) {
            const int n = i >> 4, w4 = i & 15;
            *(uint4*)&lds_u[n * 68 + w4 * 4] = bg4[n * 16 + w4];
        }
    }
    __syncthreads();

    const int row0 = blockIdx.x * 64 + wave * 16;
    const int rowa = min(row0 + nl, M - 1);   // clamped A row for this lane

    // A fragments: lane holds A[rowa][ks*32 + q*8 .. +7], 4 k-steps
    short8 a[4];
    if (AF32) {
#pragma unroll
        for (int ks = 0; ks < 4; ++ks) {
            const float4 p = *(const float4*)(Af + (size_t)rowa * HH + ks * 32 + q * 8);
            const float4 r = *(const float4*)(Af + (size_t)rowa * HH + ks * 32 + q * 8 + 4);
            U4S8 cv;
            cv.u = make_uint4(packbf(sani(p.x), sani(p.y)), packbf(sani(p.z), sani(p.w)),
                              packbf(sani(r.x), sani(r.y)), packbf(sani(r.z), sani(r.w)));
            a[ks] = cv.s;
        }
    } else {
#pragma unroll
        for (int ks = 0; ks < 4; ++ks) {
            U4S8 cv;
            cv.u = *(const uint4*)(Abf + (size_t)rowa * 64 + ks * 16 + q * 4);
            a[ks] = cv.s;
        }
    }

    f32x4 acc[8];
#pragma unroll
    for (int t = 0; t < 8; ++t) acc[t] = (f32x4)0.0f;

    const unsigned short* __restrict__ bts = (const unsigned short*)lds_u;
#pragma unroll
    for (int ks = 0; ks < 4; ++ks) {
#pragma unroll
        for (int t = 0; t < 8; ++t) {
            const int n = t * 16 + nl;
            // B fragment: B[k = ks*32 + q*8 + j][n]  (ushort row stride 136)
            const short8 b = *(const short8*)(bts + n * 136 + ks * 32 + q * 8);
            acc[t] = __builtin_amdgcn_mfma_f32_16x16x32_bf16(a[ks], b, acc[t], 0, 0, 0);
        }
    }

    __syncthreads();   // all waves done reading B^T; reuse LDS for C staging

    // stage C f32: per-wave region 16 rows x 132 floats
    float* __restrict__ cs = (float*)lds_u + wave * 16 * 132;
#pragma unroll
    for (int t = 0; t < 8; ++t) {
#pragma unroll
        for (int r = 0; r < 4; ++r) {
            cs[(q * 4 + r) * 132 + t * 16 + nl] = acc[t][r];   // C[row=q*4+r][col]
        }
    }
    __syncthreads();

    // pack + store: lane covers row rr, 32-col segment seg
    const int rr = lane & 15;
    const int seg = lane >> 4;
    const int rowg = row0 + rr;
    if (rowg < M) {
        const float4* crow = (const float4*)(cs + rr * 132) + seg * 8;
#pragma unroll
        for (int j = 0; j < 4; ++j) {
            const float4 fa = crow[2 * j];
            const float4 fb = crow[2 * j + 1];
            const uint4 o = make_uint4(packbf(fa.x, fa.y), packbf(fa.z, fa.w),
                                       packbf(fb.x, fb.y), packbf(fb.z, fb.w));
            *(uint4*)(C + (size_t)rowg * 64 + seg * 16 + j * 4) = o;
        }
    }
}

// ---------------------------------------------------------------------------
// Fused aggregate + bias + BN(eval) + ReLU; bf16 in, bf16 out.
// ---------------------------------------------------------------------------
__global__ __launch_bounds__(256) void aggregate_k(
    const unsigned* __restrict__ hpre, const int* __restrict__ csr,
    const int* __restrict__ offs, const int* __restrict__ cnt,
    const float* __restrict__ dinv,
    const float* __restrict__ bnsc, const float* __restrict__ bnsh,
    unsigned* __restrict__ xout) {
    const int v = __builtin_amdgcn_readfirstlane(blockIdx.x * 4 + (threadIdx.x >> 6));
    const int lane = threadIdx.x & 63;
    const int cg = lane & 15;
    const int sub = lane >> 4;
    const int c8 = cg * 8;

    const float dv = dinv[v];
    const int start = offs[v];
    const int n = cnt[v];
    const char* __restrict__ hb = (const char*)hpre;   // row = 256 B
    const unsigned cgo = (unsigned)(cg << 4);

    float acc[8];
#pragma unroll
    for (int j = 0; j < 8; ++j) acc[j] = 0.0f;

    for (int i = 0; i < n; i += 16) {
        const int e0 = i + sub, e1 = i + 4 + sub, e2 = i + 8 + sub, e3 = i + 12 + sub;
        const int nm1 = n - 1;
        const int s0 = csr[start + min(e0, nm1)];
        const int s1 = csr[start + min(e1, nm1)];
        const int s2 = csr[start + min(e2, nm1)];
        const int s3 = csr[start + min(e3, nm1)];
        const float w0 = (e0 < n) ? dinv[s0] : 0.0f;
        const float w1 = (e1 < n) ? dinv[s1] : 0.0f;
        const float w2 = (e2 < n) ? dinv[s2] : 0.0f;
        const float w3 = (e3 < n) ? dinv[s3] : 0.0f;
        const uint4 r0 = *(const uint4*)(hb + (((unsigned)s0 << 8) | cgo));
        const uint4 r1 = *(const uint4*)(hb + (((unsigned)s1 << 8) | cgo));
        const uint4 r2 = *(const uint4*)(hb + (((unsigned)s2 << 8) | cgo));
        const uint4 r3 = *(const uint4*)(hb + (((unsigned)s3 << 8) | cgo));

        acc[0] += w0 * bflo(r0.x); acc[1] += w0 * bfhi(r0.x);
        acc[2] += w0 * bflo(r0.y); acc[3] += w0 * bfhi(r0.y);
        acc[4] += w0 * bflo(r0.z); acc[5] += w0 * bfhi(r0.z);
        acc[6] += w0 * bflo(r0.w); acc[7] += w0 * bfhi(r0.w);
        acc[0] += w1 * bflo(r1.x); acc[1] += w1 * bfhi(r1.x);
        acc[2] += w1 * bflo(r1.y); acc[3] += w1 * bfhi(r1.y);
        acc[4] += w1 * bflo(r1.z); acc[5] += w1 * bfhi(r1.z);
        acc[6] += w1 * bflo(r1.w); acc[7] += w1 * bfhi(r1.w);
        acc[0] += w2 * bflo(r2.x); acc[1] += w2 * bfhi(r2.x);
        acc[2] += w2 * bflo(r2.y); acc[3] += w2 * bfhi(r2.y);
        acc[4] += w2 * bflo(r2.z); acc[5] += w2 * bfhi(r2.z);
        acc[6] += w2 * bflo(r2.w); acc[7] += w2 * bfhi(r2.w);
        acc[0] += w3 * bflo(r3.x); acc[1] += w3 * bfhi(r3.x);
        acc[2] += w3 * bflo(r3.y); acc[3] += w3 * bfhi(r3.y);
        acc[4] += w3 * bflo(r3.z); acc[5] += w3 * bfhi(r3.z);
        acc[6] += w3 * bflo(r3.w); acc[7] += w3 * bfhi(r3.w);
    }

#pragma unroll
    for (int j = 0; j < 8; ++j) {
        acc[j] += __shfl_xor(acc[j], 16);
        acc[j] += __shfl_xor(acc[j], 32);
    }

    if (sub == 0) {
        const float4 sca = *(const float4*)(bnsc + c8);
        const float4 scb = *(const float4*)(bnsc + c8 + 4);
        const float4 sha = *(const float4*)(bnsh + c8);
        const float4 shb = *(const float4*)(bnsh + c8 + 4);
        const uint4 rs = *(const uint4*)(hb + (((unsigned)v << 8) | cgo));
        const float dv2 = dv * dv;
        const float s0 = dv * acc[0] + dv2 * bflo(rs.x);
        const float s1 = dv * acc[1] + dv2 * bfhi(rs.x);
        const float s2 = dv * acc[2] + dv2 * bflo(rs.y);
        const float s3 = dv * acc[3] + dv2 * bfhi(rs.y);
        const float s4 = dv * acc[4] + dv2 * bflo(rs.z);
        const float s5 = dv * acc[5] + dv2 * bfhi(rs.z);
        const float s6 = dv * acc[6] + dv2 * bflo(rs.w);
        const float s7 = dv * acc[7] + dv2 * bfhi(rs.w);
        const float y0 = fmaxf(s0 * sca.x + sha.x, 0.0f);
        const float y1 = fmaxf(s1 * sca.y + sha.y, 0.0f);
        const float y2 = fmaxf(s2 * sca.z + sha.z, 0.0f);
        const float y3 = fmaxf(s3 * sca.w + sha.w, 0.0f);
        const float y4 = fmaxf(s4 * scb.x + shb.x, 0.0f);
        const float y5 = fmaxf(s5 * scb.y + shb.y, 0.0f);
        const float y6 = fmaxf(s6 * scb.z + shb.z, 0.0f);
        const float y7 = fmaxf(s7 * scb.w + shb.w, 0.0f);
        *(uint4*)(xout + (size_t)v * 64 + cg * 4) =
            make_uint4(packbf(y0, y1), packbf(y2, y3), packbf(y4, y5), packbf(y6, y7));
    }
}

// ---------------------------------------------------------------------------
// Global mean pool (batch sorted, bf16 input) + 2-layer FC head.
// ---------------------------------------------------------------------------
__global__ __launch_bounds__(128) void pool_head_k(
    const unsigned* __restrict__ x, const int* __restrict__ batch,
    const int* __restrict__ flags,
    const float* __restrict__ fw1, const float* __restrict__ fb1,
    const float* __restrict__ fw2, const float* __restrict__ fb2,
    float* __restrict__ out) {
    __shared__ float pooled[128];
    __shared__ float hid[64];
    const int g = blockIdx.x;
    const int tid = threadIdx.x;
    const bool b64 = flags[1] != 0;

    int lo = 0, hi = NN;
    while (lo < hi) {
        const int mid = (lo + hi) >> 1;
        const int bv = b64 ? batch[2 * mid] : batch[mid];
        if (bv < g) lo = mid + 1; else hi = mid;
    }
    const int beg = lo;
    lo = beg; hi = NN;
    while (lo < hi) {
        const int mid = (lo + hi) >> 1;
        const int bv = b64 ? batch[2 * mid] : batch[mid];
        if (bv < g + 1) lo = mid + 1; else hi = mid;
    }
    const int end = lo;
    const int cntn = end - beg;

    const int uo = tid >> 1;           // uint index within row
    const bool hiw = (tid & 1) != 0;
    float s0 = 0.f, s1 = 0.f;
    int i = beg;
    for (; i + 2 <= end; i += 2) {
        const unsigned ua = x[(size_t)(i + 0) * 64 + uo];
        const unsigned ub = x[(size_t)(i + 1) * 64 + uo];
        s0 += hiw ? bfhi(ua) : bflo(ua);
        s1 += hiw ? bfhi(ub) : bflo(ub);
    }
    for (; i < end; ++i) {
        const unsigned ua = x[(size_t)i * 64 + uo];
        s0 += hiw ? bfhi(ua) : bflo(ua);
    }
    pooled[tid] = (s0 + s1) / (float)(cntn > 0 ? cntn : 1);
    __syncthreads();

    if (tid < 64) {
        float a = fb1[tid];
#pragma unroll 4
        for (int k = 0; k < 128; ++k) a += pooled[k] * fw1[k * 64 + tid];
        hid[tid] = fmaxf(a, 0.0f);
    }
    __syncthreads();
    if (tid < 10) {
        float a = fb2[tid];
#pragma unroll
        for (int k = 0; k < 64; ++k) a += hid[k] * fw2[k * 10 + tid];
        out[g * 10 + tid] = a;
    }
}

// ---------------------------------------------------------------------------
// launch
// ---------------------------------------------------------------------------
extern "C" void kernel_launch(void* const* d_in, const int* in_sizes, int n_in,
                              void* d_out, int out_size, void* d_ws, size_t ws_size,
                              hipStream_t stream) {
    const float* x_in  = (const float*)d_in[0];
    const int*   ei    = (const int*)d_in[1];
    const int*   batch = (const int*)d_in[2];
    const float* w1 = (const float*)d_in[3];
    const float* b1 = (const float*)d_in[4];
    const float* w2 = (const float*)d_in[5];
    const float* b2 = (const float*)d_in[6];
    const float* w3 = (const float*)d_in[7];
    const float* b3 = (const float*)d_in[8];
    const float* g1 = (const float*)d_in[9];
    const float* be1 = (const float*)d_in[10];
    const float* m1 = (const float*)d_in[11];
    const float* v1 = (const float*)d_in[12];
    const float* g2 = (const float*)d_in[13];
    const float* be2 = (const float*)d_in[14];
    const float* m2 = (const float*)d_in[15];
    const float* v2 = (const float*)d_in[16];
    const float* g3 = (const float*)d_in[17];
    const float* be3 = (const float*)d_in[18];
    const float* m3 = (const float*)d_in[19];
    const float* v3 = (const float*)d_in[20];
    const float* fw1 = (const float*)d_in[21];
    const float* fb1 = (const float*)d_in[22];
    const float* fw2 = (const float*)d_in[23];
    const float* fb2 = (const float*)d_in[24];
    float* out = (float*)d_out;

    size_t off = 0;
    char* base = (char*)d_ws;
    auto alloc = [&](size_t bytes) -> void* {
        void* p = base + off;
        off += (bytes + 255) & ~(size_t)255;
        return p;
    };
    int*      degcnt = (int*)alloc((size_t)NN * 4);
    float*    dinv   = (float*)alloc((size_t)NN * 4);
    int*      offs   = (int*)alloc((size_t)NN * 4);
    int*      cursor = (int*)alloc((size_t)NBK * 4);
    int*      flags  = (int*)alloc(256);
    float*    bnsc   = (float*)alloc(3 * 128 * 4);
    float*    bnsh   = (float*)alloc(3 * 128 * 4);
    unsigned* btg    = (unsigned*)alloc(3 * 8192 * 4);            // bf16 B^T x3
    int*      csr    = (int*)alloc((size_t)NBK * CAPB * 4);
    unsigned* pairs  = (unsigned*)alloc((size_t)NBK * CAPB * 4);
    unsigned* bufx   = (unsigned*)alloc((size_t)NN * 64 * 4);     // bf16 x2 packed
    unsigned* hpre   = (unsigned*)alloc((size_t)NN * 64 * 4);     // bf16 x2 packed
    if (off > ws_size) return;

    detect_k<<<1, 64, 0, stream>>>(ei, batch, flags);
    cursinit_k<<<1, 512, 0, stream>>>(cursor);
    bnprep_k<<<1, 128, 0, stream>>>(b1, g1, be1, m1, v1,
                                    b2, g2, be2, m2, v2,
                                    b3, g3, be3, m3, v3, bnsc, bnsh);
    wprep_k<<<96, 256, 0, stream>>>(w1, w2, w3, btg);
    passA_k<<<PASSA_WG, 256, 0, stream>>>(ei, flags, cursor, pairs);
    passB_k<<<NBK, 256, 0, stream>>>(pairs, cursor, offs, degcnt, dinv, csr);

    const int ggrid = (NN + 63) / 64;          // 1563
    const int agrid = NN / 4;                  // 25000

    gemm_mfma_k<true><<<ggrid, 256, 0, stream>>>(x_in, nullptr, btg, hpre, NN);
    aggregate_k<<<agrid, 256, 0, stream>>>(hpre, csr, offs, degcnt, dinv,
                                           bnsc, bnsh, bufx);
    gemm_mfma_k<false><<<ggrid, 256, 0, stream>>>(nullptr, bufx, btg + 8192, hpre, NN);
    aggregate_k<<<agrid, 256, 0, stream>>>(hpre, csr, offs, degcnt, dinv,
                                           bnsc + 128, bnsh + 128, bufx);
    gemm_mfma_k<false><<<ggrid, 256, 0, stream>>>(nullptr, bufx, btg + 16384, hpre, NN);
    aggregate_k<<<agrid, 256, 0, stream>>>(hpre, csr, offs, degcnt, dinv,
                                           bnsc + 256, bnsh + 256, bufx);

    pool_head_k<<<GG, 128, 0, stream>>>(bufx, batch, flags,
                                        fw1, fb1, fw2, fb2, out);
}

// Round 7
// 470.129 us; speedup vs baseline: 1.8794x; 1.0495x over previous
//
#include <hip/hip_runtime.h>
#include <math.h>

#define NN 100000
#define EE 1600000
#define GG 256
#define HH 128
#define BSH 8                 /* 256 nodes per bucket */
#define NBK 391               /* ceil(NN/256) */
#define PASSA_WG 391          /* ceil(EE/4096) */
#define CAPB 5120             /* fixed region capacity per bucket (mean 4092, +16 sigma) */

typedef __attribute__((ext_vector_type(8))) short short8;   // 8 bf16 (4 VGPRs)
typedef __attribute__((ext_vector_type(4))) float f32x4;    // MFMA acc

union U4S8 { uint4 u; short8 s; };

// ---------------------------------------------------------------------------
// bf16 helpers (RNE pack, cheap unpack)
// ---------------------------------------------------------------------------
static __device__ __forceinline__ unsigned bf16rne(float f) {
    const unsigned u = __float_as_uint(f);
    return (u + 0x7fffu + ((u >> 16) & 1u)) >> 16;
}
static __device__ __forceinline__ unsigned packbf(float a, float b) {
    return bf16rne(a) | (bf16rne(b) << 16);
}
static __device__ __forceinline__ float bflo(unsigned u) { return __uint_as_float(u << 16); }
static __device__ __forceinline__ float bfhi(unsigned u) { return __uint_as_float(u & 0xffff0000u); }

// ---------------------------------------------------------------------------
// dtype layout detection (int32 vs int64 device layout for edge_index/batch)
// ---------------------------------------------------------------------------
__global__ void detect_k(const int* __restrict__ ei, const int* __restrict__ batch,
                         int* __restrict__ flags) {
    if (threadIdx.x == 0 && blockIdx.x == 0) {
        int e64 = 1;
        for (int j = 0; j < 8; ++j) {
            if (ei[2 * EE - 1 - 2 * j] != 0) { e64 = 0; break; }
        }
        flags[0] = e64;
        flags[1] = (batch[NN - 1] == 0) ? 1 : 0;
    }
}

// cursor[b] = b*CAPB (fixed per-bucket region bases)
__global__ __launch_bounds__(512) void cursinit_k(int* __restrict__ cursor) {
    const int b = blockIdx.x * 512 + threadIdx.x;
    if (b < NBK) cursor[b] = b * CAPB;
}

// ---------------------------------------------------------------------------
// BN eval coefficients, hoisted (all 3 layers).
// ---------------------------------------------------------------------------
__global__ void bnprep_k(const float* __restrict__ b1, const float* __restrict__ g1,
                         const float* __restrict__ be1, const float* __restrict__ m1,
                         const float* __restrict__ v1,
                         const float* __restrict__ b2, const float* __restrict__ g2,
                         const float* __restrict__ be2, const float* __restrict__ m2,
                         const float* __restrict__ v2,
                         const float* __restrict__ b3, const float* __restrict__ g3,
                         const float* __restrict__ be3, const float* __restrict__ m3,
                         const float* __restrict__ v3,
                         float* __restrict__ sc, float* __restrict__ sh) {
    const int c = threadIdx.x;
    float s;
    s = g1[c] / sqrtf(v1[c] + 1e-5f);
    sc[c] = s;           sh[c] = (b1[c] - m1[c]) * s + be1[c];
    s = g2[c] / sqrtf(v2[c] + 1e-5f);
    sc[128 + c] = s;     sh[128 + c] = (b2[c] - m2[c]) * s + be2[c];
    s = g3[c] / sqrtf(v3[c] + 1e-5f);
    sc[256 + c] = s;     sh[256 + c] = (b3[c] - m3[c]) * s + be3[c];
}

// ---------------------------------------------------------------------------
// Weights -> bf16 B^T[n][k] (packed 2 bf16/uint, 64 uints per n-row), x3.
// ---------------------------------------------------------------------------
__global__ __launch_bounds__(256) void wprep_k(const float* __restrict__ w1,
                                               const float* __restrict__ w2,
                                               const float* __restrict__ w3,
                                               unsigned* __restrict__ bt) {
    const int id = blockIdx.x * 256 + threadIdx.x;   // 3*8192 total
    if (id >= 3 * 8192) return;
    const int w = id >> 13;
    const int rem = id & 8191;
    const int n = rem >> 6;
    const int kk = rem & 63;                          // k-pair
    const float* W = (w == 0) ? w1 : (w == 1) ? w2 : w3;
    bt[id] = packbf(W[(2 * kk) * HH + n], W[(2 * kk + 1) * HH + n]);
}

// ---------------------------------------------------------------------------
// pass A: bucket-grouped packed-pair scatter into fixed regions.
// packed = (dloc<<17) | src
// ---------------------------------------------------------------------------
__global__ __launch_bounds__(256) void passA_k(const int* __restrict__ ei,
                                               const int* __restrict__ flags,
                                               int* __restrict__ cursor,
                                               unsigned* __restrict__ pairs) {
    __shared__ int h[NBK];
    __shared__ int rbase[NBK];
    const int tid = threadIdx.x;
    for (int i = tid; i < NBK; i += 256) h[i] = 0;
    __syncthreads();
    const bool e64 = flags[0] != 0;
    const int base = blockIdx.x * 4096;
    int scache[16], dcache[16];
#pragma unroll
    for (int j = 0; j < 16; ++j) {
        const int e = base + j * 256 + tid;
        int s = -1, d = 0;
        if (e < EE) {
            s = e64 ? ei[2 * e] : ei[e];
            d = e64 ? ei[2 * (EE + e)] : ei[EE + e];
            atomicAdd(&h[d >> BSH], 1);
        }
        scache[j] = s; dcache[j] = d;
    }
    __syncthreads();
    for (int i = tid; i < NBK; i += 256) {
        const int c = h[i];
        rbase[i] = c ? atomicAdd(&cursor[i], c) : 0;
    }
    __syncthreads();
    for (int i = tid; i < NBK; i += 256) h[i] = 0;
    __syncthreads();
#pragma unroll
    for (int j = 0; j < 16; ++j) {
        const int s = scache[j];
        if (s >= 0) {
            const int d = dcache[j];
            const int b = d >> BSH;
            const int r = atomicAdd(&h[b], 1);
            pairs[rbase[b] + r] = ((unsigned)(d & 255) << 17) | (unsigned)s;
        }
    }
}

// ---------------------------------------------------------------------------
// pass B: one wg per bucket -> offs/degcnt/dinv + bucketed CSR.
// ---------------------------------------------------------------------------
__global__ __launch_bounds__(256) void passB_k(const unsigned* __restrict__ pairs,
                                               const int* __restrict__ cursor,
                                               int* __restrict__ offs,
                                               int* __restrict__ degcnt,
                                               float* __restrict__ dinv,
                                               int* __restrict__ csr) {
    __shared__ unsigned pk[CAPB];
    __shared__ int cnt[256];
    __shared__ int loff[256];
    __shared__ int sc[256];
    const int tid = threadIdx.x;
    const int b = blockIdx.x;
    const int p0 = b * CAPB;
    const int np = cursor[b] - p0;
    const int nb0 = b << BSH;
    const int nnode = (NN - nb0 < 256) ? (NN - nb0) : 256;

    cnt[tid] = 0;
    __syncthreads();
    for (int i = tid; i < np; i += 256) {
        const unsigned p = pairs[p0 + i];
        pk[i] = p;
        atomicAdd(&cnt[p >> 17], 1);
    }
    __syncthreads();
    sc[tid] = cnt[tid];
    __syncthreads();
    for (int off = 1; off < 256; off <<= 1) {
        int t = (tid >= off) ? sc[tid - off] : 0;
        __syncthreads();
        sc[tid] += t;
        __syncthreads();
    }
    const int ex = sc[tid] - cnt[tid];
    loff[tid] = ex;
    if (tid < nnode) {
        const int node = nb0 + tid;
        offs[node] = p0 + ex;
        degcnt[node] = cnt[tid];
        dinv[node] = 1.0f / sqrtf((float)(cnt[tid] + 1));
    }
    __syncthreads();
    cnt[tid] = 0;
    __syncthreads();
    for (int i = tid; i < np; i += 256) {
        const unsigned p = pk[i];
        const int dl = (int)(p >> 17);
        const int r = atomicAdd(&cnt[dl], 1);
        csr[p0 + loff[dl] + r] = (int)(p & 0x1FFFFu);
    }
}

// ---------------------------------------------------------------------------
// MFMA bf16 GEMM: C[M,128](bf16) = A[M,128] @ B[128,128], B given as
// bf16 B^T[n][k]. Block = 256 thr = 4 waves; wave = 16-row strip, 8 C-tiles
// of 16x16, K = 4 steps of 32 (v_mfma_f32_16x16x32_bf16).
// ---------------------------------------------------------------------------
static __device__ __forceinline__ float sani(float v) {
    if (isnan(v)) return 0.0f;
    if (isinf(v)) return v > 0.0f ? 1e6f : -1e6f;
    return v;
}

template <bool AF32>
__global__ __launch_bounds__(256) void gemm_mfma_k(const float* __restrict__ Af,
                                                   const unsigned* __restrict__ Abf,
                                                   const unsigned* __restrict__ btg,
                                                   unsigned* __restrict__ C, int M) {
    __shared__ unsigned lds_u[8704];   // 34816 B: B^T[128][68 uints], then C-staging
    const int tid = threadIdx.x;
    const int wave = tid >> 6;
    const int lane = tid & 63;
    const int nl = lane & 15;          // n within tile / m-row of A
    const int q = lane >> 4;           // k-quad

    // stage B^T: 128 rows x 64 uints (btg) -> LDS rows of 68 uints
    {
        const uint4* __restrict__ bg4 = (const uint4*)btg;
        for (int i = tid; i < 2048; i += 256) {
            const int n = i >> 4, w4 = i & 15;
            *(uint4*)&lds_u[n * 68 + w4 * 4] = bg4[n * 16 + w4];
        }
    }
    __syncthreads();

    const int row0 = blockIdx.x * 64 + wave * 16;
    const int rowa = min(row0 + nl, M - 1);   // clamped A row for this lane

    // A fragments: lane holds A[rowa][ks*32 + q*8 .. +7], 4 k-steps
    short8 a[4];
    if (AF32) {
#pragma unroll
        for (int ks = 0; ks < 4; ++ks) {
            const float4 p = *(const float4*)(Af + (size_t)rowa * HH + ks * 32 + q * 8);
            const float4 r = *(const float4*)(Af + (size_t)rowa * HH + ks * 32 + q * 8 + 4);
            U4S8 cv;
            cv.u = make_uint4(packbf(sani(p.x), sani(p.y)), packbf(sani(p.z), sani(p.w)),
                              packbf(sani(r.x), sani(r.y)), packbf(sani(r.z), sani(r.w)));
            a[ks] = cv.s;
        }
    } else {
#pragma unroll
        for (int ks = 0; ks < 4; ++ks) {
            U4S8 cv;
            cv.u = *(const uint4*)(Abf + (size_t)rowa * 64 + ks * 16 + q * 4);
            a[ks] = cv.s;
        }
    }

    f32x4 acc[8];
#pragma unroll
    for (int t = 0; t < 8; ++t) acc[t] = (f32x4)0.0f;

    const unsigned short* __restrict__ bts = (const unsigned short*)lds_u;
#pragma unroll
    for (int ks = 0; ks < 4; ++ks) {
#pragma unroll
        for (int t = 0; t < 8; ++t) {
            const int n = t * 16 + nl;
            const short8 b = *(const short8*)(bts + n * 136 + ks * 32 + q * 8);
            acc[t] = __builtin_amdgcn_mfma_f32_16x16x32_bf16(a[ks], b, acc[t], 0, 0, 0);
        }
    }

    __syncthreads();   // all waves done reading B^T; reuse LDS for C staging

    // stage C f32: per-wave region 16 rows x 132 floats
    float* __restrict__ cs = (float*)lds_u + wave * 16 * 132;
#pragma unroll
    for (int t = 0; t < 8; ++t) {
#pragma unroll
        for (int r = 0; r < 4; ++r) {
            cs[(q * 4 + r) * 132 + t * 16 + nl] = acc[t][r];   // C[row=q*4+r][col]
        }
    }
    __syncthreads();

    // pack + store: lane covers row rr, 32-col segment seg
    const int rr = lane & 15;
    const int seg = lane >> 4;
    const int rowg = row0 + rr;
    if (rowg < M) {
        const float4* crow = (const float4*)(cs + rr * 132) + seg * 8;
#pragma unroll
        for (int j = 0; j < 4; ++j) {
            const float4 fa = crow[2 * j];
            const float4 fb = crow[2 * j + 1];
            const uint4 o = make_uint4(packbf(fa.x, fa.y), packbf(fa.z, fa.w),
                                       packbf(fb.x, fb.y), packbf(fb.z, fb.w));
            *(uint4*)(C + (size_t)rowg * 64 + seg * 16 + j * 4) = o;
        }
    }
}

// ---------------------------------------------------------------------------
// Fused aggregate + bias + BN(eval) + ReLU; bf16 in, bf16 out.
// ---------------------------------------------------------------------------
__global__ __launch_bounds__(256) void aggregate_k(
    const unsigned* __restrict__ hpre, const int* __restrict__ csr,
    const int* __restrict__ offs, const int* __restrict__ cnt,
    const float* __restrict__ dinv,
    const float* __restrict__ bnsc, const float* __restrict__ bnsh,
    unsigned* __restrict__ xout) {
    const int v = __builtin_amdgcn_readfirstlane(blockIdx.x * 4 + (threadIdx.x >> 6));
    const int lane = threadIdx.x & 63;
    const int cg = lane & 15;
    const int sub = lane >> 4;
    const int c8 = cg * 8;

    const float dv = dinv[v];
    const int start = offs[v];
    const int n = cnt[v];
    const char* __restrict__ hb = (const char*)hpre;   // row = 256 B
    const unsigned cgo = (unsigned)(cg << 4);

    float acc[8];
#pragma unroll
    for (int j = 0; j < 8; ++j) acc[j] = 0.0f;

    for (int i = 0; i < n; i += 16) {
        const int e0 = i + sub, e1 = i + 4 + sub, e2 = i + 8 + sub, e3 = i + 12 + sub;
        const int nm1 = n - 1;
        const int s0 = csr[start + min(e0, nm1)];
        const int s1 = csr[start + min(e1, nm1)];
        const int s2 = csr[start + min(e2, nm1)];
        const int s3 = csr[start + min(e3, nm1)];
        const float w0 = (e0 < n) ? dinv[s0] : 0.0f;
        const float w1 = (e1 < n) ? dinv[s1] : 0.0f;
        const float w2 = (e2 < n) ? dinv[s2] : 0.0f;
        const float w3 = (e3 < n) ? dinv[s3] : 0.0f;
        const uint4 r0 = *(const uint4*)(hb + (((unsigned)s0 << 8) | cgo));
        const uint4 r1 = *(const uint4*)(hb + (((unsigned)s1 << 8) | cgo));
        const uint4 r2 = *(const uint4*)(hb + (((unsigned)s2 << 8) | cgo));
        const uint4 r3 = *(const uint4*)(hb + (((unsigned)s3 << 8) | cgo));

        acc[0] += w0 * bflo(r0.x); acc[1] += w0 * bfhi(r0.x);
        acc[2] += w0 * bflo(r0.y); acc[3] += w0 * bfhi(r0.y);
        acc[4] += w0 * bflo(r0.z); acc[5] += w0 * bfhi(r0.z);
        acc[6] += w0 * bflo(r0.w); acc[7] += w0 * bfhi(r0.w);
        acc[0] += w1 * bflo(r1.x); acc[1] += w1 * bfhi(r1.x);
        acc[2] += w1 * bflo(r1.y); acc[3] += w1 * bfhi(r1.y);
        acc[4] += w1 * bflo(r1.z); acc[5] += w1 * bfhi(r1.z);
        acc[6] += w1 * bflo(r1.w); acc[7] += w1 * bfhi(r1.w);
        acc[0] += w2 * bflo(r2.x); acc[1] += w2 * bfhi(r2.x);
        acc[2] += w2 * bflo(r2.y); acc[3] += w2 * bfhi(r2.y);
        acc[4] += w2 * bflo(r2.z); acc[5] += w2 * bfhi(r2.z);
        acc[6] += w2 * bflo(r2.w); acc[7] += w2 * bfhi(r2.w);
        acc[0] += w3 * bflo(r3.x); acc[1] += w3 * bfhi(r3.x);
        acc[2] += w3 * bflo(r3.y); acc[3] += w3 * bfhi(r3.y);
        acc[4] += w3 * bflo(r3.z); acc[5] += w3 * bfhi(r3.z);
        acc[6] += w3 * bflo(r3.w); acc[7] += w3 * bfhi(r3.w);
    }

#pragma unroll
    for (int j = 0; j < 8; ++j) {
        acc[j] += __shfl_xor(acc[j], 16);
        acc[j] += __shfl_xor(acc[j], 32);
    }

    if (sub == 0) {
        const float4 sca = *(const float4*)(bnsc + c8);
        const float4 scb = *(const float4*)(bnsc + c8 + 4);
        const float4 sha = *(const float4*)(bnsh + c8);
        const float4 shb = *(const float4*)(bnsh + c8 + 4);
        const uint4 rs = *(const uint4*)(hb + (((unsigned)v << 8) | cgo));
        const float dv2 = dv * dv;
        const float s0 = dv * acc[0] + dv2 * bflo(rs.x);
        const float s1 = dv * acc[1] + dv2 * bfhi(rs.x);
        const float s2 = dv * acc[2] + dv2 * bflo(rs.y);
        const float s3 = dv * acc[3] + dv2 * bfhi(rs.y);
        const float s4 = dv * acc[4] + dv2 * bflo(rs.z);
        const float s5 = dv * acc[5] + dv2 * bfhi(rs.z);
        const float s6 = dv * acc[6] + dv2 * bflo(rs.w);
        const float s7 = dv * acc[7] + dv2 * bfhi(rs.w);
        const float y0 = fmaxf(s0 * sca.x + sha.x, 0.0f);
        const float y1 = fmaxf(s1 * sca.y + sha.y, 0.0f);
        const float y2 = fmaxf(s2 * sca.z + sha.z, 0.0f);
        const float y3 = fmaxf(s3 * sca.w + sha.w, 0.0f);
        const float y4 = fmaxf(s4 * scb.x + shb.x, 0.0f);
        const float y5 = fmaxf(s5 * scb.y + shb.y, 0.0f);
        const float y6 = fmaxf(s6 * scb.z + shb.z, 0.0f);
        const float y7 = fmaxf(s7 * scb.w + shb.w, 0.0f);
        *(uint4*)(xout + (size_t)v * 64 + cg * 4) =
            make_uint4(packbf(y0, y1), packbf(y2, y3), packbf(y4, y5), packbf(y6, y7));
    }
}

// ---------------------------------------------------------------------------
// Parallel mean-pool, phase 1: per-wave 16-row run accumulation + boundary
// atomics into psum[g][128] (f32) and gcnt[g]. batch is sorted.
// ---------------------------------------------------------------------------
__global__ __launch_bounds__(256) void pool_sum_k(
    const unsigned* __restrict__ x, const int* __restrict__ batch,
    const int* __restrict__ flags, float* __restrict__ psum,
    int* __restrict__ gcnt) {
    const int wave = threadIdx.x >> 6;
    const int lane = threadIdx.x & 63;
    const int row0 = blockIdx.x * 64 + wave * 16;
    if (row0 >= NN) return;
    const bool b64 = flags[1] != 0;

    float sx = 0.0f, sy = 0.0f;
    int cur = -1, runlen = 0;
#pragma unroll
    for (int r = 0; r < 16; ++r) {
        const int row = row0 + r;
        if (row >= NN) break;
        const int g = b64 ? batch[2 * row] : batch[row];
        if (g != cur) {
            if (cur >= 0) {
                atomicAdd(&psum[cur * HH + lane * 2 + 0], sx);
                atomicAdd(&psum[cur * HH + lane * 2 + 1], sy);
                if (lane == 0) atomicAdd(&gcnt[cur], runlen);
            }
            cur = g; sx = 0.0f; sy = 0.0f; runlen = 0;
        }
        const unsigned u = x[(size_t)row * 64 + lane];
        sx += bflo(u);
        sy += bfhi(u);
        ++runlen;
    }
    if (cur >= 0) {
        atomicAdd(&psum[cur * HH + lane * 2 + 0], sx);
        atomicAdd(&psum[cur * HH + lane * 2 + 1], sy);
        if (lane == 0) atomicAdd(&gcnt[cur], runlen);
    }
}

// ---------------------------------------------------------------------------
// Head: pooled = psum/cnt, then fc1+ReLU+fc2. One block per graph.
// ---------------------------------------------------------------------------
__global__ __launch_bounds__(128) void head_k(
    const float* __restrict__ psum, const int* __restrict__ gcnt,
    const float* __restrict__ fw1, const float* __restrict__ fb1,
    const float* __restrict__ fw2, const float* __restrict__ fb2,
    float* __restrict__ out) {
    __shared__ float pooled[128];
    __shared__ float hid[64];
    const int g = blockIdx.x;
    const int tid = threadIdx.x;

    const int cntn = gcnt[g];
    pooled[tid] = psum[g * HH + tid] / (float)(cntn > 0 ? cntn : 1);
    __syncthreads();

    if (tid < 64) {
        float a = fb1[tid];
#pragma unroll 4
        for (int k = 0; k < 128; ++k) a += pooled[k] * fw1[k * 64 + tid];
        hid[tid] = fmaxf(a, 0.0f);
    }
    __syncthreads();
    if (tid < 10) {
        float a = fb2[tid];
#pragma unroll
        for (int k = 0; k < 64; ++k) a += hid[k] * fw2[k * 10 + tid];
        out[g * 10 + tid] = a;
    }
}

// ---------------------------------------------------------------------------
// launch
// ---------------------------------------------------------------------------
extern "C" void kernel_launch(void* const* d_in, const int* in_sizes, int n_in,
                              void* d_out, int out_size, void* d_ws, size_t ws_size,
                              hipStream_t stream) {
    const float* x_in  = (const float*)d_in[0];
    const int*   ei    = (const int*)d_in[1];
    const int*   batch = (const int*)d_in[2];
    const float* w1 = (const float*)d_in[3];
    const float* b1 = (const float*)d_in[4];
    const float* w2 = (const float*)d_in[5];
    const float* b2 = (const float*)d_in[6];
    const float* w3 = (const float*)d_in[7];
    const float* b3 = (const float*)d_in[8];
    const float* g1 = (const float*)d_in[9];
    const float* be1 = (const float*)d_in[10];
    const float* m1 = (const float*)d_in[11];
    const float* v1 = (const float*)d_in[12];
    const float* g2 = (const float*)d_in[13];
    const float* be2 = (const float*)d_in[14];
    const float* m2 = (const float*)d_in[15];
    const float* v2 = (const float*)d_in[16];
    const float* g3 = (const float*)d_in[17];
    const float* be3 = (const float*)d_in[18];
    const float* m3 = (const float*)d_in[19];
    const float* v3 = (const float*)d_in[20];
    const float* fw1 = (const float*)d_in[21];
    const float* fb1 = (const float*)d_in[22];
    const float* fw2 = (const float*)d_in[23];
    const float* fb2 = (const float*)d_in[24];
    float* out = (float*)d_out;

    size_t off = 0;
    char* base = (char*)d_ws;
    auto alloc = [&](size_t bytes) -> void* {
        void* p = base + off;
        off += (bytes + 255) & ~(size_t)255;
        return p;
    };
    int*      degcnt = (int*)alloc((size_t)NN * 4);
    float*    dinv   = (float*)alloc((size_t)NN * 4);
    int*      offs   = (int*)alloc((size_t)NN * 4);
    int*      cursor = (int*)alloc((size_t)NBK * 4);
    int*      flags  = (int*)alloc(256);
    float*    bnsc   = (float*)alloc(3 * 128 * 4);
    float*    bnsh   = (float*)alloc(3 * 128 * 4);
    unsigned* btg    = (unsigned*)alloc(3 * 8192 * 4);            // bf16 B^T x3
    float*    psum   = (float*)alloc((size_t)GG * HH * 4);        // pooled sums f32
    int*      gcnt   = (int*)alloc((size_t)GG * 4);
    int*      csr    = (int*)alloc((size_t)NBK * CAPB * 4);
    unsigned* pairs  = (unsigned*)alloc((size_t)NBK * CAPB * 4);
    unsigned* bufx   = (unsigned*)alloc((size_t)NN * 64 * 4);     // bf16 x2 packed
    unsigned* hpre   = (unsigned*)alloc((size_t)NN * 64 * 4);     // bf16 x2 packed
    if (off > ws_size) return;

    detect_k<<<1, 64, 0, stream>>>(ei, batch, flags);
    cursinit_k<<<1, 512, 0, stream>>>(cursor);
    bnprep_k<<<1, 128, 0, stream>>>(b1, g1, be1, m1, v1,
                                    b2, g2, be2, m2, v2,
                                    b3, g3, be3, m3, v3, bnsc, bnsh);
    wprep_k<<<96, 256, 0, stream>>>(w1, w2, w3, btg);
    hipMemsetAsync(psum, 0, (size_t)GG * HH * 4, stream);
    hipMemsetAsync(gcnt, 0, (size_t)GG * 4, stream);
    passA_k<<<PASSA_WG, 256, 0, stream>>>(ei, flags, cursor, pairs);
    passB_k<<<NBK, 256, 0, stream>>>(pairs, cursor, offs, degcnt, dinv, csr);

    const int ggrid = (NN + 63) / 64;          // 1563
    const int agrid = NN / 4;                  // 25000

    gemm_mfma_k<true><<<ggrid, 256, 0, stream>>>(x_in, nullptr, btg, hpre, NN);
    aggregate_k<<<agrid, 256, 0, stream>>>(hpre, csr, offs, degcnt, dinv,
                                           bnsc, bnsh, bufx);
    gemm_mfma_k<false><<<ggrid, 256, 0, stream>>>(nullptr, bufx, btg + 8192, hpre, NN);
    aggregate_k<<<agrid, 256, 0, stream>>>(hpre, csr, offs, degcnt, dinv,
                                           bnsc + 128, bnsh + 128, bufx);
    gemm_mfma_k<false><<<ggrid, 256, 0, stream>>>(nullptr, bufx, btg + 16384, hpre, NN);
    aggregate_k<<<agrid, 256, 0, stream>>>(hpre, csr, offs, degcnt, dinv,
                                           bnsc + 256, bnsh + 256, bufx);

    pool_sum_k<<<ggrid, 256, 0, stream>>>(bufx, batch, flags, psum, gcnt);
    head_k<<<GG, 128, 0, stream>>>(psum, gcnt, fw1, fb1, fw2, fb2, out);
}

// Round 8
// 456.497 us; speedup vs baseline: 1.9356x; 1.0299x over previous
//
#include <hip/hip_runtime.h>
#include <math.h>

#define NN 100000
#define EE 1600000
#define GG 256
#define HH 128
#define BSH 8                 /* 256 nodes per bucket */
#define NBK 391               /* ceil(NN/256) */
#define PASSA_WG 391          /* ceil(EE/4096) */
#define CAPB 5632             /* per-bucket region: edges(~4092) + self+pad(<=1024), +14 sigma */

typedef __attribute__((ext_vector_type(8))) short short8;   // 8 bf16 (4 VGPRs)
typedef __attribute__((ext_vector_type(4))) float f32x4;    // MFMA acc

union U4S8 { uint4 u; short8 s; };

// ---------------------------------------------------------------------------
// bf16 helpers (RNE pack, cheap unpack)
// ---------------------------------------------------------------------------
static __device__ __forceinline__ unsigned bf16rne(float f) {
    const unsigned u = __float_as_uint(f);
    return (u + 0x7fffu + ((u >> 16) & 1u)) >> 16;
}
static __device__ __forceinline__ unsigned packbf(float a, float b) {
    return bf16rne(a) | (bf16rne(b) << 16);
}
static __device__ __forceinline__ float bflo(unsigned u) { return __uint_as_float(u << 16); }
static __device__ __forceinline__ float bfhi(unsigned u) { return __uint_as_float(u & 0xffff0000u); }

// ---------------------------------------------------------------------------
// dtype layout detection (int32 vs int64 device layout for edge_index/batch)
// ---------------------------------------------------------------------------
__global__ void detect_k(const int* __restrict__ ei, const int* __restrict__ batch,
                         int* __restrict__ flags) {
    if (threadIdx.x == 0 && blockIdx.x == 0) {
        int e64 = 1;
        for (int j = 0; j < 8; ++j) {
            if (ei[2 * EE - 1 - 2 * j] != 0) { e64 = 0; break; }
        }
        flags[0] = e64;
        flags[1] = (batch[NN - 1] == 0) ? 1 : 0;
    }
}

// cursor[b] = b*CAPB (fixed per-bucket region bases)
__global__ __launch_bounds__(512) void cursinit_k(int* __restrict__ cursor) {
    const int b = blockIdx.x * 512 + threadIdx.x;
    if (b < NBK) cursor[b] = b * CAPB;
}

// ---------------------------------------------------------------------------
// BN eval coefficients, hoisted (all 3 layers).
// ---------------------------------------------------------------------------
__global__ void bnprep_k(const float* __restrict__ b1, const float* __restrict__ g1,
                         const float* __restrict__ be1, const float* __restrict__ m1,
                         const float* __restrict__ v1,
                         const float* __restrict__ b2, const float* __restrict__ g2,
                         const float* __restrict__ be2, const float* __restrict__ m2,
                         const float* __restrict__ v2,
                         const float* __restrict__ b3, const float* __restrict__ g3,
                         const float* __restrict__ be3, const float* __restrict__ m3,
                         const float* __restrict__ v3,
                         float* __restrict__ sc, float* __restrict__ sh) {
    const int c = threadIdx.x;
    float s;
    s = g1[c] / sqrtf(v1[c] + 1e-5f);
    sc[c] = s;           sh[c] = (b1[c] - m1[c]) * s + be1[c];
    s = g2[c] / sqrtf(v2[c] + 1e-5f);
    sc[128 + c] = s;     sh[128 + c] = (b2[c] - m2[c]) * s + be2[c];
    s = g3[c] / sqrtf(v3[c] + 1e-5f);
    sc[256 + c] = s;     sh[256 + c] = (b3[c] - m3[c]) * s + be3[c];
}

// ---------------------------------------------------------------------------
// Weights -> bf16 B^T[n][k] (packed 2 bf16/uint, 64 uints per n-row), x3.
// ---------------------------------------------------------------------------
__global__ __launch_bounds__(256) void wprep_k(const float* __restrict__ w1,
                                               const float* __restrict__ w2,
                                               const float* __restrict__ w3,
                                               unsigned* __restrict__ bt) {
    const int id = blockIdx.x * 256 + threadIdx.x;   // 3*8192 total
    if (id >= 3 * 8192) return;
    const int w = id >> 13;
    const int rem = id & 8191;
    const int n = rem >> 6;
    const int kk = rem & 63;                          // k-pair
    const float* W = (w == 0) ? w1 : (w == 1) ? w2 : w3;
    bt[id] = packbf(W[(2 * kk) * HH + n], W[(2 * kk + 1) * HH + n]);
}

// ---------------------------------------------------------------------------
// pass A: bucket-grouped packed-pair scatter into fixed regions.
// packed = (dloc<<17) | src
// ---------------------------------------------------------------------------
__global__ __launch_bounds__(256) void passA_k(const int* __restrict__ ei,
                                               const int* __restrict__ flags,
                                               int* __restrict__ cursor,
                                               unsigned* __restrict__ pairs) {
    __shared__ int h[NBK];
    __shared__ int rbase[NBK];
    const int tid = threadIdx.x;
    for (int i = tid; i < NBK; i += 256) h[i] = 0;
    __syncthreads();
    const bool e64 = flags[0] != 0;
    const int base = blockIdx.x * 4096;
    int scache[16], dcache[16];
#pragma unroll
    for (int j = 0; j < 16; ++j) {
        const int e = base + j * 256 + tid;
        int s = -1, d = 0;
        if (e < EE) {
            s = e64 ? ei[2 * e] : ei[e];
            d = e64 ? ei[2 * (EE + e)] : ei[EE + e];
            atomicAdd(&h[d >> BSH], 1);
        }
        scache[j] = s; dcache[j] = d;
    }
    __syncthreads();
    for (int i = tid; i < NBK; i += 256) {
        const int c = h[i];
        rbase[i] = c ? atomicAdd(&cursor[i], c) : 0;
    }
    __syncthreads();
    for (int i = tid; i < NBK; i += 256) h[i] = 0;
    __syncthreads();
#pragma unroll
    for (int j = 0; j < 16; ++j) {
        const int s = scache[j];
        if (s >= 0) {
            const int d = dcache[j];
            const int b = d >> BSH;
            const int r = atomicAdd(&h[b], 1);
            pairs[rbase[b] + r] = ((unsigned)(d & 255) << 17) | (unsigned)s;
        }
    }
}

// ---------------------------------------------------------------------------
// pass B: one wg per bucket -> offs/degcnt/dinv + bucketed CSR with
// self-inclusive padding: each node's list = [edges..., self, NN-sentinels]
// padded to a multiple of 4 (sentinel NN = zero row in hpre).
// ---------------------------------------------------------------------------
__global__ __launch_bounds__(256) void passB_k(const unsigned* __restrict__ pairs,
                                               const int* __restrict__ cursor,
                                               int* __restrict__ offs,
                                               int* __restrict__ degcnt,
                                               float* __restrict__ dinv,
                                               int* __restrict__ csr) {
    __shared__ unsigned pk[CAPB];
    __shared__ int cnt[256];
    __shared__ int loff[256];
    __shared__ int sc[256];
    const int tid = threadIdx.x;
    const int b = blockIdx.x;
    const int p0 = b * CAPB;
    const int np = cursor[b] - p0;           // real edges in bucket
    const int nb0 = b << BSH;
    const int nnode = (NN - nb0 < 256) ? (NN - nb0) : 256;

    cnt[tid] = 0;
    __syncthreads();
    for (int i = tid; i < np; i += 256) {
        const unsigned p = pairs[p0 + i];
        pk[i] = p;
        atomicAdd(&cnt[p >> 17], 1);
    }
    __syncthreads();
    const int creal = cnt[tid];
    const int cpad = (tid < nnode) ? ((creal + 4) & ~3) : 0;   // +self, pad to 4
    sc[tid] = cpad;
    __syncthreads();
    for (int off = 1; off < 256; off <<= 1) {
        int t = (tid >= off) ? sc[tid - off] : 0;
        __syncthreads();
        sc[tid] += t;
        __syncthreads();
    }
    const int ex = sc[tid] - cpad;
    loff[tid] = ex;
    if (tid < nnode) {
        const int node = nb0 + tid;
        offs[node] = p0 + ex;
        degcnt[node] = creal;
        dinv[node] = 1.0f / sqrtf((float)(creal + 1));
    }
    __syncthreads();
    cnt[tid] = 0;
    __syncthreads();
    for (int i = tid; i < np; i += 256) {
        const unsigned p = pk[i];
        const int dl = (int)(p >> 17);
        const int r = atomicAdd(&cnt[dl], 1);
        csr[p0 + loff[dl] + r] = (int)(p & 0x1FFFFu);
    }
    // pad slots [creal, cpad): self then sentinels (disjoint from scatter slots)
    if (tid < nnode) {
        const int basep = p0 + loff[tid];
        csr[basep + creal] = nb0 + tid;
        for (int j = creal + 1; j < cpad; ++j) csr[basep + j] = NN;
    }
}

// ---------------------------------------------------------------------------
// MFMA bf16 GEMM: C[M,128](bf16, row-scaled by dinv) = A[M,128] @ B[128,128].
// Row M (sentinel) is written as zeros. B given as bf16 B^T[n][k].
// Block = 256 thr = 4 waves; wave = 16-row strip, 8 C-tiles of 16x16,
// K = 4 steps of 32 (v_mfma_f32_16x16x32_bf16).
// ---------------------------------------------------------------------------
static __device__ __forceinline__ float sani(float v) {
    if (isnan(v)) return 0.0f;
    if (isinf(v)) return v > 0.0f ? 1e6f : -1e6f;
    return v;
}

template <bool AF32>
__global__ __launch_bounds__(256) void gemm_mfma_k(const float* __restrict__ Af,
                                                   const unsigned* __restrict__ Abf,
                                                   const unsigned* __restrict__ btg,
                                                   const float* __restrict__ dinv,
                                                   unsigned* __restrict__ C, int M) {
    __shared__ unsigned lds_u[8704];   // 34816 B: B^T[128][68 uints], then C-staging
    const int tid = threadIdx.x;
    const int wave = tid >> 6;
    const int lane = tid & 63;
    const int nl = lane & 15;          // n within tile / m-row of A
    const int q = lane >> 4;           // k-quad

    // stage B^T: 128 rows x 64 uints (btg) -> LDS rows of 68 uints
    {
        const uint4* __restrict__ bg4 = (const uint4*)btg;
        for (int i = tid; i < 2048; i += 256) {
            const int n = i >> 4, w4 = i & 15;
            *(uint4*)&lds_u[n * 68 + w4 * 4] = bg4[n * 16 + w4];
        }
    }
    __syncthreads();

    const int row0 = blockIdx.x * 64 + wave * 16;
    const int rowa = min(row0 + nl, M - 1);   // clamped A row for this lane

    // A fragments: lane holds A[rowa][ks*32 + q*8 .. +7], 4 k-steps
    short8 a[4];
    if (AF32) {
#pragma unroll
        for (int ks = 0; ks < 4; ++ks) {
            const float4 p = *(const float4*)(Af + (size_t)rowa * HH + ks * 32 + q * 8);
            const float4 r = *(const float4*)(Af + (size_t)rowa * HH + ks * 32 + q * 8 + 4);
            U4S8 cv;
            cv.u = make_uint4(packbf(sani(p.x), sani(p.y)), packbf(sani(p.z), sani(p.w)),
                              packbf(sani(r.x), sani(r.y)), packbf(sani(r.z), sani(r.w)));
            a[ks] = cv.s;
        }
    } else {
#pragma unroll
        for (int ks = 0; ks < 4; ++ks) {
            U4S8 cv;
            cv.u = *(const uint4*)(Abf + (size_t)rowa * 64 + ks * 16 + q * 4);
            a[ks] = cv.s;
        }
    }

    f32x4 acc[8];
#pragma unroll
    for (int t = 0; t < 8; ++t) acc[t] = (f32x4)0.0f;

    const unsigned short* __restrict__ bts = (const unsigned short*)lds_u;
#pragma unroll
    for (int ks = 0; ks < 4; ++ks) {
#pragma unroll
        for (int t = 0; t < 8; ++t) {
            const int n = t * 16 + nl;
            const short8 b = *(const short8*)(bts + n * 136 + ks * 32 + q * 8);
            acc[t] = __builtin_amdgcn_mfma_f32_16x16x32_bf16(a[ks], b, acc[t], 0, 0, 0);
        }
    }

    __syncthreads();   // all waves done reading B^T; reuse LDS for C staging

    // stage C f32: per-wave region 16 rows x 132 floats
    float* __restrict__ cs = (float*)lds_u + wave * 16 * 132;
#pragma unroll
    for (int t = 0; t < 8; ++t) {
#pragma unroll
        for (int r = 0; r < 4; ++r) {
            cs[(q * 4 + r) * 132 + t * 16 + nl] = acc[t][r];   // C[row=q*4+r][col]
        }
    }
    __syncthreads();

    // pack + store (row-scaled by dinv): lane covers row rr, 32-col segment seg
    const int rr = lane & 15;
    const int seg = lane >> 4;
    const int rowg = row0 + rr;
    if (rowg < M) {
        const float dsc = dinv[rowg];
        const float4* crow = (const float4*)(cs + rr * 132) + seg * 8;
#pragma unroll
        for (int j = 0; j < 4; ++j) {
            const float4 fa = crow[2 * j];
            const float4 fb = crow[2 * j + 1];
            const uint4 o = make_uint4(packbf(dsc * fa.x, dsc * fa.y),
                                       packbf(dsc * fa.z, dsc * fa.w),
                                       packbf(dsc * fb.x, dsc * fb.y),
                                       packbf(dsc * fb.z, dsc * fb.w));
            *(uint4*)(C + (size_t)rowg * 64 + seg * 16 + j * 4) = o;
        }
    } else if (rowg == M) {
        // sentinel zero row for padded CSR gathers
        const uint4 z = make_uint4(0, 0, 0, 0);
#pragma unroll
        for (int j = 0; j < 4; ++j)
            *(uint4*)(C + (size_t)M * 64 + seg * 16 + j * 4) = z;
    }
}

// ---------------------------------------------------------------------------
// Fused aggregate + BN(eval) + ReLU over pre-scaled rows; bf16 in/out.
// List is self-inclusive and padded to x4 with zero-row sentinels, so the
// inner loop is pure gather+add: acc = sum(rows); y = relu(dv*acc*sc + sh).
// One wave per node; 16 lanes x 8 channels; sub = lane>>4 strides entries.
// ---------------------------------------------------------------------------
__global__ __launch_bounds__(256) void aggregate_k(
    const unsigned* __restrict__ hpre, const int* __restrict__ csr,
    const int* __restrict__ offs, const int* __restrict__ cnt,
    const float* __restrict__ dinv,
    const float* __restrict__ bnsc, const float* __restrict__ bnsh,
    unsigned* __restrict__ xout) {
    const int v = __builtin_amdgcn_readfirstlane(blockIdx.x * 4 + (threadIdx.x >> 6));
    const int lane = threadIdx.x & 63;
    const int cg = lane & 15;
    const int sub = lane >> 4;
    const int c8 = cg * 8;

    const float dv = dinv[v];
    const int start = offs[v];
    const int npad = (cnt[v] + 4) & ~3;      // +self, padded to x4 (matches passB)
    const char* __restrict__ hb = (const char*)hpre;   // row = 256 B
    const unsigned cgo = (unsigned)(cg << 4);

    float acc[8];
#pragma unroll
    for (int j = 0; j < 8; ++j) acc[j] = 0.0f;

    int i = 0;
    for (; i + 8 <= npad; i += 8) {          // 8 entries/iter: 2 gathers in flight
        const int sA = csr[start + i + sub];
        const int sB = csr[start + i + 4 + sub];
        const uint4 rA = *(const uint4*)(hb + (((unsigned)sA << 8) | cgo));
        const uint4 rB = *(const uint4*)(hb + (((unsigned)sB << 8) | cgo));
        acc[0] += bflo(rA.x) + bflo(rB.x);
        acc[1] += bfhi(rA.x) + bfhi(rB.x);
        acc[2] += bflo(rA.y) + bflo(rB.y);
        acc[3] += bfhi(rA.y) + bfhi(rB.y);
        acc[4] += bflo(rA.z) + bflo(rB.z);
        acc[5] += bfhi(rA.z) + bfhi(rB.z);
        acc[6] += bflo(rA.w) + bflo(rB.w);
        acc[7] += bfhi(rA.w) + bfhi(rB.w);
    }
    if (i < npad) {                          // wave-uniform tail of exactly 4
        const int s = csr[start + i + sub];
        const uint4 r = *(const uint4*)(hb + (((unsigned)s << 8) | cgo));
        acc[0] += bflo(r.x); acc[1] += bfhi(r.x);
        acc[2] += bflo(r.y); acc[3] += bfhi(r.y);
        acc[4] += bflo(r.z); acc[5] += bfhi(r.z);
        acc[6] += bflo(r.w); acc[7] += bfhi(r.w);
    }

#pragma unroll
    for (int j = 0; j < 8; ++j) {
        acc[j] += __shfl_xor(acc[j], 16);
        acc[j] += __shfl_xor(acc[j], 32);
    }

    if (sub == 0) {
        const float4 sca = *(const float4*)(bnsc + c8);
        const float4 scb = *(const float4*)(bnsc + c8 + 4);
        const float4 sha = *(const float4*)(bnsh + c8);
        const float4 shb = *(const float4*)(bnsh + c8 + 4);
        const float y0 = fmaxf(dv * acc[0] * sca.x + sha.x, 0.0f);
        const float y1 = fmaxf(dv * acc[1] * sca.y + sha.y, 0.0f);
        const float y2 = fmaxf(dv * acc[2] * sca.z + sha.z, 0.0f);
        const float y3 = fmaxf(dv * acc[3] * sca.w + sha.w, 0.0f);
        const float y4 = fmaxf(dv * acc[4] * scb.x + shb.x, 0.0f);
        const float y5 = fmaxf(dv * acc[5] * scb.y + shb.y, 0.0f);
        const float y6 = fmaxf(dv * acc[6] * scb.z + shb.z, 0.0f);
        const float y7 = fmaxf(dv * acc[7] * scb.w + shb.w, 0.0f);
        *(uint4*)(xout + (size_t)v * 64 + cg * 4) =
            make_uint4(packbf(y0, y1), packbf(y2, y3), packbf(y4, y5), packbf(y6, y7));
    }
}

// ---------------------------------------------------------------------------
// Parallel mean-pool, phase 1: per-wave 16-row run accumulation + boundary
// atomics into psum[g][128] (f32) and gcnt[g]. batch is sorted.
// ---------------------------------------------------------------------------
__global__ __launch_bounds__(256) void pool_sum_k(
    const unsigned* __restrict__ x, const int* __restrict__ batch,
    const int* __restrict__ flags, float* __restrict__ psum,
    int* __restrict__ gcnt) {
    const int wave = threadIdx.x >> 6;
    const int lane = threadIdx.x & 63;
    const int row0 = blockIdx.x * 64 + wave * 16;
    if (row0 >= NN) return;
    const bool b64 = flags[1] != 0;

    float sx = 0.0f, sy = 0.0f;
    int cur = -1, runlen = 0;
#pragma unroll
    for (int r = 0; r < 16; ++r) {
        const int row = row0 + r;
        if (row >= NN) break;
        const int g = b64 ? batch[2 * row] : batch[row];
        if (g != cur) {
            if (cur >= 0) {
                atomicAdd(&psum[cur * HH + lane * 2 + 0], sx);
                atomicAdd(&psum[cur * HH + lane * 2 + 1], sy);
                if (lane == 0) atomicAdd(&gcnt[cur], runlen);
            }
            cur = g; sx = 0.0f; sy = 0.0f; runlen = 0;
        }
        const unsigned u = x[(size_t)row * 64 + lane];
        sx += bflo(u);
        sy += bfhi(u);
        ++runlen;
    }
    if (cur >= 0) {
        atomicAdd(&psum[cur * HH + lane * 2 + 0], sx);
        atomicAdd(&psum[cur * HH + lane * 2 + 1], sy);
        if (lane == 0) atomicAdd(&gcnt[cur], runlen);
    }
}

// ---------------------------------------------------------------------------
// Head: pooled = psum/cnt, then fc1+ReLU+fc2. One block per graph.
// ---------------------------------------------------------------------------
__global__ __launch_bounds__(128) void head_k(
    const float* __restrict__ psum, const int* __restrict__ gcnt,
    const float* __restrict__ fw1, const float* __restrict__ fb1,
    const float* __restrict__ fw2, const float* __restrict__ fb2,
    float* __restrict__ out) {
    __shared__ float pooled[128];
    __shared__ float hid[64];
    const int g = blockIdx.x;
    const int tid = threadIdx.x;

    const int cntn = gcnt[g];
    pooled[tid] = psum[g * HH + tid] / (float)(cntn > 0 ? cntn : 1);
    __syncthreads();

    if (tid < 64) {
        float a = fb1[tid];
#pragma unroll 4
        for (int k = 0; k < 128; ++k) a += pooled[k] * fw1[k * 64 + tid];
        hid[tid] = fmaxf(a, 0.0f);
    }
    __syncthreads();
    if (tid < 10) {
        float a = fb2[tid];
#pragma unroll
        for (int k = 0; k < 64; ++k) a += hid[k] * fw2[k * 10 + tid];
        out[g * 10 + tid] = a;
    }
}

// ---------------------------------------------------------------------------
// launch
// ---------------------------------------------------------------------------
extern "C" void kernel_launch(void* const* d_in, const int* in_sizes, int n_in,
                              void* d_out, int out_size, void* d_ws, size_t ws_size,
                              hipStream_t stream) {
    const float* x_in  = (const float*)d_in[0];
    const int*   ei    = (const int*)d_in[1];
    const int*   batch = (const int*)d_in[2];
    const float* w1 = (const float*)d_in[3];
    const float* b1 = (const float*)d_in[4];
    const float* w2 = (const float*)d_in[5];
    const float* b2 = (const float*)d_in[6];
    const float* w3 = (const float*)d_in[7];
    const float* b3 = (const float*)d_in[8];
    const float* g1 = (const float*)d_in[9];
    const float* be1 = (const float*)d_in[10];
    const float* m1 = (const float*)d_in[11];
    const float* v1 = (const float*)d_in[12];
    const float* g2 = (const float*)d_in[13];
    const float* be2 = (const float*)d_in[14];
    const float* m2 = (const float*)d_in[15];
    const float* v2 = (const float*)d_in[16];
    const float* g3 = (const float*)d_in[17];
    const float* be3 = (const float*)d_in[18];
    const float* m3 = (const float*)d_in[19];
    const float* v3 = (const float*)d_in[20];
    const float* fw1 = (const float*)d_in[21];
    const float* fb1 = (const float*)d_in[22];
    const float* fw2 = (const float*)d_in[23];
    const float* fb2 = (const float*)d_in[24];
    float* out = (float*)d_out;

    size_t off = 0;
    char* base = (char*)d_ws;
    auto alloc = [&](size_t bytes) -> void* {
        void* p = base + off;
        off += (bytes + 255) & ~(size_t)255;
        return p;
    };
    int*      degcnt = (int*)alloc((size_t)NN * 4);
    float*    dinv   = (float*)alloc((size_t)NN * 4);
    int*      offs   = (int*)alloc((size_t)NN * 4);
    int*      cursor = (int*)alloc((size_t)NBK * 4);
    int*      flags  = (int*)alloc(256);
    float*    bnsc   = (float*)alloc(3 * 128 * 4);
    float*    bnsh   = (float*)alloc(3 * 128 * 4);
    unsigned* btg    = (unsigned*)alloc(3 * 8192 * 4);            // bf16 B^T x3
    float*    psum   = (float*)alloc((size_t)GG * HH * 4);        // pooled sums f32
    int*      gcnt   = (int*)alloc((size_t)GG * 4);
    int*      csr    = (int*)alloc((size_t)NBK * CAPB * 4);
    unsigned* pairs  = (unsigned*)alloc((size_t)NBK * CAPB * 4);
    unsigned* bufx   = (unsigned*)alloc((size_t)NN * 64 * 4);         // bf16 x2 packed
    unsigned* hpre   = (unsigned*)alloc((size_t)(NN + 1) * 64 * 4);   // + sentinel row
    if (off > ws_size) return;

    detect_k<<<1, 64, 0, stream>>>(ei, batch, flags);
    cursinit_k<<<1, 512, 0, stream>>>(cursor);
    bnprep_k<<<1, 128, 0, stream>>>(b1, g1, be1, m1, v1,
                                    b2, g2, be2, m2, v2,
                                    b3, g3, be3, m3, v3, bnsc, bnsh);
    wprep_k<<<96, 256, 0, stream>>>(w1, w2, w3, btg);
    hipMemsetAsync(psum, 0, (size_t)GG * HH * 4, stream);
    hipMemsetAsync(gcnt, 0, (size_t)GG * 4, stream);
    passA_k<<<PASSA_WG, 256, 0, stream>>>(ei, flags, cursor, pairs);
    passB_k<<<NBK, 256, 0, stream>>>(pairs, cursor, offs, degcnt, dinv, csr);

    const int ggrid = (NN + 63) / 64;          // 1563 (covers row NN sentinel too)
    const int agrid = NN / 4;                  // 25000

    gemm_mfma_k<true><<<ggrid, 256, 0, stream>>>(x_in, nullptr, btg, dinv, hpre, NN);
    aggregate_k<<<agrid, 256, 0, stream>>>(hpre, csr, offs, degcnt, dinv,
                                           bnsc, bnsh, bufx);
    gemm_mfma_k<false><<<ggrid, 256, 0, stream>>>(nullptr, bufx, btg + 8192, dinv, hpre, NN);
    aggregate_k<<<agrid, 256, 0, stream>>>(hpre, csr, offs, degcnt, dinv,
                                           bnsc + 128, bnsh + 128, bufx);
    gemm_mfma_k<false><<<ggrid, 256, 0, stream>>>(nullptr, bufx, btg + 16384, dinv, hpre, NN);
    aggregate_k<<<agrid, 256, 0, stream>>>(hpre, csr, offs, degcnt, dinv,
                                           bnsc + 256, bnsh + 256, bufx);

    pool_sum_k<<<ggrid, 256, 0, stream>>>(bufx, batch, flags, psum, gcnt);
    head_k<<<GG, 128, 0, stream>>>(psum, gcnt, fw1, fb1, fw2, fb2, out);
}